// Round 12
// baseline (1066.053 us; speedup 1.0000x reference)
//
#include <hip/hip_runtime.h>

typedef __bf16 bf16;
typedef bf16 bf16x8 __attribute__((ext_vector_type(8)));
typedef bf16 bf16x4 __attribute__((ext_vector_type(4)));
typedef bf16 bf16x2 __attribute__((ext_vector_type(2)));
typedef float f32x4 __attribute__((ext_vector_type(4)));
typedef float f32x2 __attribute__((ext_vector_type(2)));

#define S_LEN 1024
#define DIM 2048
#define NH 16
#define NKVH 4
#define HD 128
#define HID 8192
#define VOCAB 32000
#define QKV_N 3072
#define W13_N 16384
#define IMG_K 1176
#define NIMG 256

#define AS1 __attribute__((address_space(1)))
#define AS3 __attribute__((address_space(3)))

__device__ inline f32x4 mfma16(bf16x8 a, bf16x8 b, f32x4 c) {
  return __builtin_amdgcn_mfma_f32_16x16x32_bf16(a, b, c, 0, 0, 0);
}

// ---------------- embed ----------------
__global__ void embed_kernel(const int* __restrict__ tok, const float* __restrict__ emb,
                             float* __restrict__ x) {
  int s = blockIdx.x, t = threadIdx.x;
  int id = tok[s];
  const float* er = emb + (size_t)id * DIM;
  float* xr = x + (size_t)s * DIM;
  *(f32x4*)(xr + t * 8)     = *(const f32x4*)(er + t * 8);
  *(f32x4*)(xr + t * 8 + 4) = *(const f32x4*)(er + t * 8 + 4);
}

// ---------------- fp32 -> bf16 converts ----------------
__global__ void cvt_kernel(const float* __restrict__ in, bf16* __restrict__ o, int n) {
  int i = blockIdx.x * 256 + threadIdx.x;
  if (i < n) o[i] = (bf16)in[i];
}
__global__ void cvt4_kernel(const float* __restrict__ in, bf16* __restrict__ o, int n4) {
  int i = blockIdx.x * 256 + threadIdx.x;
  if (i < n4) {
    f32x4 v = *(const f32x4*)(in + (size_t)i * 4);
    bf16x4 b;
    b[0] = (bf16)v[0]; b[1] = (bf16)v[1]; b[2] = (bf16)v[2]; b[3] = (bf16)v[3];
    *(bf16x4*)(o + (size_t)i * 4) = b;
  }
}

// ---------------- rmsnorm (x fp32 -> bf16) ----------------
template<int USE_W>
__global__ void rmsnorm_kernel(const float* __restrict__ x, const float* __restrict__ w,
                               bf16* __restrict__ o) {
  const int row = blockIdx.x, t = threadIdx.x;
  const float* xr = x + (size_t)row * DIM;
  f32x4 a = *(const f32x4*)(xr + t * 8);
  f32x4 b = *(const f32x4*)(xr + t * 8 + 4);
  float ss = a[0]*a[0] + a[1]*a[1] + a[2]*a[2] + a[3]*a[3]
           + b[0]*b[0] + b[1]*b[1] + b[2]*b[2] + b[3]*b[3];
#pragma unroll
  for (int off = 1; off < 64; off <<= 1) ss += __shfl_xor(ss, off);
  __shared__ float red[4];
  if ((t & 63) == 0) red[t >> 6] = ss;
  __syncthreads();
  ss = red[0] + red[1] + red[2] + red[3];
  float r = rsqrtf(ss * (1.0f / DIM) + 1e-6f);
  bf16x8 ov;
  if (USE_W) {
    f32x4 w1 = *(const f32x4*)(w + t * 8);
    f32x4 w2v = *(const f32x4*)(w + t * 8 + 4);
    ov[0] = (bf16)(a[0]*r*w1[0]); ov[1] = (bf16)(a[1]*r*w1[1]);
    ov[2] = (bf16)(a[2]*r*w1[2]); ov[3] = (bf16)(a[3]*r*w1[3]);
    ov[4] = (bf16)(b[0]*r*w2v[0]); ov[5] = (bf16)(b[1]*r*w2v[1]);
    ov[6] = (bf16)(b[2]*r*w2v[2]); ov[7] = (bf16)(b[3]*r*w2v[3]);
  } else {
    ov[0] = (bf16)(a[0]*r); ov[1] = (bf16)(a[1]*r);
    ov[2] = (bf16)(a[2]*r); ov[3] = (bf16)(a[3]*r);
    ov[4] = (bf16)(b[0]*r); ov[5] = (bf16)(b[1]*r);
    ov[6] = (bf16)(b[2]*r); ov[7] = (bf16)(b[3]*r);
  }
  *(bf16x8*)(o + (size_t)row * DIM + t * 8) = ov;
}

// ---------------- qkv post: per-head rms + rope, write q/k/vT bf16 ----------------
__global__ void qkvpost_kernel(const float* __restrict__ qkv, const float* __restrict__ f1,
                               const float* __restrict__ f2, bf16* __restrict__ qb,
                               bf16* __restrict__ kb, bf16* __restrict__ vtb) {
  int s = blockIdx.x, t = threadIdx.x;
  __shared__ float cs[64], sn[64];
  if (t < 64) {
    float ang = (t < 32) ? f1[(size_t)s * 32 + t] : f2[(size_t)s * 32 + (t - 32)];
    cs[t] = cosf(ang);
    sn[t] = sinf(ang);
  }
  __syncthreads();
  int w = t >> 6, lane = t & 63;
  for (int hh = w; hh < 24; hh += 4) {
    const float* base = qkv + (size_t)s * QKV_N + hh * HD;
    f32x2 e = *(const f32x2*)(base + lane * 2);
    if (hh < 20) {
      float ssum = e[0]*e[0] + e[1]*e[1];
#pragma unroll
      for (int off = 1; off < 64; off <<= 1) ssum += __shfl_xor(ssum, off);
      float r = rsqrtf(ssum * (1.0f / HD) + 1e-6f);
      float x1 = e[0] * r, x2 = e[1] * r;
      float c = cs[lane], s2 = sn[lane];
      bf16x2 ov;
      ov[0] = (bf16)(x1 * c - x2 * s2);
      ov[1] = (bf16)(x1 * s2 + x2 * c);
      if (hh < 16)
        *(bf16x2*)(qb + ((size_t)hh * S_LEN + s) * HD + lane * 2) = ov;
      else
        *(bf16x2*)(kb + ((size_t)(hh - 16) * S_LEN + s) * HD + lane * 2) = ov;
    } else {
      int kv = hh - 20;
      vtb[((size_t)kv * HD + lane * 2) * S_LEN + s]     = (bf16)e[0];
      vtb[((size_t)kv * HD + lane * 2 + 1) * S_LEN + s] = (bf16)e[1];
    }
  }
}

// ---------------- flash attention, KV-split across 4 waves ----------------
__global__ __launch_bounds__(256) void attn_kernel(const bf16* __restrict__ qb,
                                                   const bf16* __restrict__ kb,
                                                   const bf16* __restrict__ vtb,
                                                   const float* __restrict__ sinks,
                                                   bf16* __restrict__ out) {
  const int h = blockIdx.y, qs = blockIdx.x;
  const int w = threadIdx.x >> 6, lane = threadIdx.x & 63;
  const int lo = lane & 15, hi = lane >> 4;
  const int q0 = qs * 16;
  const int q = q0 + lo;
  const int kvh = h >> 2;
  const bf16* Q = qb + (size_t)h * S_LEN * HD;
  const bf16* Kp = kb + (size_t)kvh * S_LEN * HD;
  const bf16* Vt = vtb + (size_t)kvh * HD * S_LEN;
  const float scale = 0.08838834764831845f;

  __shared__ float accS[4][64 * 36];
  __shared__ float mS[4][16], lS[4][16];

  bf16x8 qf[4];
#pragma unroll
  for (int ks = 0; ks < 4; ++ks)
    qf[ks] = *(const bf16x8*)(Q + (size_t)q * HD + ks * 32 + hi * 8);

  f32x4 accT[8];
#pragma unroll
  for (int i = 0; i < 8; ++i) accT[i] = (f32x4){0.f, 0.f, 0.f, 0.f};
  float mrow = -3e38f, lrow = 0.f;

  const int nt = (q0 + 15) / 32 + 1;
  for (int tile = w; tile < nt; tile += 4) {
    const int kv0 = tile * 32;
    f32x4 st0 = (f32x4){0.f,0.f,0.f,0.f}, st1 = (f32x4){0.f,0.f,0.f,0.f};
#pragma unroll
    for (int ks = 0; ks < 4; ++ks) {
      const bf16* kbase = Kp + (size_t)(kv0 + lo) * HD + ks * 32 + hi * 8;
      bf16x8 k0f = *(const bf16x8*)(kbase);
      bf16x8 k1f = *(const bf16x8*)(kbase + 16 * HD);
      st0 = mfma16(k0f, qf[ks], st0);
      st1 = mfma16(k1f, qf[ks], st1);
    }
    float p[2][4];
    float pmax = -3e38f;
#pragma unroll
    for (int r = 0; r < 4; ++r) {
      int kvg0 = kv0 + hi * 4 + r;
      float v0 = (kvg0 <= q) ? st0[r] * scale : -3e38f;
      int kvg1 = kvg0 + 16;
      float v1 = (kvg1 <= q) ? st1[r] * scale : -3e38f;
      p[0][r] = v0; p[1][r] = v1;
      pmax = fmaxf(pmax, fmaxf(v0, v1));
    }
    pmax = fmaxf(pmax, __shfl_xor(pmax, 16));
    pmax = fmaxf(pmax, __shfl_xor(pmax, 32));
    float mnew = fmaxf(mrow, pmax);
    float alpha = __expf(mrow - mnew);
    float ps = 0.f;
#pragma unroll
    for (int f = 0; f < 2; ++f)
#pragma unroll
      for (int r = 0; r < 4; ++r) {
        float e = __expf(p[f][r] - mnew);
        p[f][r] = e;
        ps += e;
      }
    ps += __shfl_xor(ps, 16);
    ps += __shfl_xor(ps, 32);
    lrow = lrow * alpha + ps;
    mrow = mnew;
#pragma unroll
    for (int fd = 0; fd < 8; ++fd) {
      accT[fd][0] *= alpha; accT[fd][1] *= alpha;
      accT[fd][2] *= alpha; accT[fd][3] *= alpha;
    }
    bf16x8 pb;
#pragma unroll
    for (int j = 0; j < 8; ++j) {
      int src = ((j >> 2) + 2 * (hi & 1)) * 16 + lo;
      float v0 = __shfl(p[0][j & 3], src);
      float v1 = __shfl(p[1][j & 3], src);
      pb[j] = (bf16)((hi >= 2) ? v1 : v0);
    }
#pragma unroll
    for (int fd = 0; fd < 8; ++fd) {
      bf16x8 vf = *(const bf16x8*)(Vt + (size_t)(fd * 16 + lo) * S_LEN + kv0 + hi * 8);
      accT[fd] = mfma16(vf, pb, accT[fd]);
    }
  }
  if (hi == 0) { mS[w][lo] = mrow; lS[w][lo] = lrow; }
  float* as = &accS[w][lane * 36];
#pragma unroll
  for (int fd = 0; fd < 8; ++fd) *(f32x4*)(as + fd * 4) = accT[fd];
  __syncthreads();
  float m0 = mS[0][lo], m1 = mS[1][lo], m2 = mS[2][lo], m3 = mS[3][lo];
  float mstar = fmaxf(fmaxf(m0, m1), fmaxf(m2, m3));
  float e0 = __expf(m0 - mstar), e1 = __expf(m1 - mstar);
  float e2 = __expf(m2 - mstar), e3 = __expf(m3 - mstar);
  float lstar = lS[0][lo]*e0 + lS[1][lo]*e1 + lS[2][lo]*e2 + lS[3][lo]*e3;
  float lse = mstar + __logf(lstar);
  float ssig = 1.f / (1.f + __expf(sinks[h] - lse));
  float sc = ssig / lstar;
#pragma unroll
  for (int f2 = 0; f2 < 2; ++f2) {
    int fd = w * 2 + f2;
    f32x4 a0 = *(const f32x4*)&accS[0][lane * 36 + fd * 4];
    f32x4 a1 = *(const f32x4*)&accS[1][lane * 36 + fd * 4];
    f32x4 a2 = *(const f32x4*)&accS[2][lane * 36 + fd * 4];
    f32x4 a3 = *(const f32x4*)&accS[3][lane * 36 + fd * 4];
#pragma unroll
    for (int r = 0; r < 4; ++r) {
      float o = a0[r]*e0 + a1[r]*e1 + a2[r]*e2 + a3[r]*e3;
      out[(size_t)q * DIM + h * HD + fd * 16 + hi * 4 + r] = (bf16)(o * sc);
    }
  }
}

// ---------------- XCD-aware (m,n) remap helper ----------------
__device__ inline void xcd_remap(int ntm, int ntn, int& mtile, int& ntile) {
  const int flat = blockIdx.x + ntm * blockIdx.y;
  const int chunk = ntm * 8;
  const int gfull = ntn >> 3;
  const int g = flat / chunk;
  if (g < gfull) {
    int rem = flat - g * chunk;
    ntile = g * 8 + (rem & 7);
    mtile = rem >> 3;
  } else {
    int rem = flat - gfull * chunk;
    int nrem = ntn - gfull * 8;
    ntile = gfull * 8 + rem % nrem;
    mtile = rem / nrem;
  }
}

enum { EPI_STORE = 0, EPI_ADD = 1, EPI_ACT = 2 };

// ---------------- GEMM (fp32-W / img / small): W fp32, reg-staged ----------------
template<int BM, int BN, int EPI, int GL>
__global__ void gemm_bt(const bf16* __restrict__ A, const float* __restrict__ W,
                        float* __restrict__ C, bf16* __restrict__ Cb,
                        int M, int N, int K, int ldc) {
  constexpr int BK = 64;
  __shared__ __align__(16) char lds[(BM + BN) * BK * 2];
  char* ldsA = lds;
  char* ldsB = lds + BM * BK * 2;
  const int t = threadIdx.x;
  int mtile, ntile;
  xcd_remap(gridDim.x, gridDim.y, mtile, ntile);
  const int m0 = mtile * BM, n0 = ntile * BN;

  const int wid = t >> 6, lane = t & 63;
  const int lo = lane & 15, hi = lane >> 4;
  const int wr = wid >> 1, wc = wid & 1;
  constexpr int TM = BM / 32, TN = BN / 32;
  constexpr int NA = BM / 32;
  constexpr int NPASS = BM / 32;
  constexpr int NW = BN / 16;

  f32x4 acc[TM][TN];
#pragma unroll
  for (int m = 0; m < TM; ++m)
#pragma unroll
    for (int n = 0; n < TN; ++n) acc[m][n] = (f32x4){0.f, 0.f, 0.f, 0.f};

  const int nk = (K + BK - 1) / BK;
  for (int kt = 0; kt < nk; ++kt) {
    const int k0 = kt * BK;
    bf16x8 av[NA];
    f32x4 wv[NW];
    if (!GL) {
#pragma unroll
      for (int i = 0; i < NA; ++i) {
        int c = t + i * 256;
        int row = c >> 3, kc = c & 7;
        int kg = k0 + kc * 8;
        bf16x8 z = {};
        av[i] = (kg < K) ? *(const bf16x8*)(A + (size_t)(m0 + row) * K + kg) : z;
      }
    }
#pragma unroll
    for (int i = 0; i < NW; ++i) {
      int c = t + i * 256;
      int row = c >> 4, kc = c & 15;
      int kg = k0 + kc * 4;
      f32x4 z = (f32x4){0.f, 0.f, 0.f, 0.f};
      wv[i] = (kg < K) ? *(const f32x4*)(W + (size_t)(n0 + row) * K + kg) : z;
    }
    __syncthreads();
    if (GL) {
#pragma unroll
      for (int i = 0; i < NPASS; ++i) {
        int row = i * 32 + (t >> 3);
        int srcb = ((t & 7) * 16) ^ ((row & 7) << 4);
        const bf16* g2 = A + (size_t)(m0 + row) * K + k0 + (srcb >> 1);
        char* l = ldsA + i * 4096 + wid * 1024;
        __builtin_amdgcn_global_load_lds((const AS1 void*)g2, (AS3 void*)l, 16, 0, 0);
      }
    } else {
#pragma unroll
      for (int i = 0; i < NA; ++i) {
        int c = t + i * 256;
        int row = c >> 3, kc = c & 7;
        int kb = (kc * 16) ^ ((row & 7) << 4);
        *(bf16x8*)(ldsA + row * 128 + kb) = av[i];
      }
    }
#pragma unroll
    for (int i = 0; i < NW; ++i) {
      int c = t + i * 256;
      int row = c >> 4, kc = c & 15;
      bf16x4 bv;
      bv[0] = (bf16)wv[i][0]; bv[1] = (bf16)wv[i][1];
      bv[2] = (bf16)wv[i][2]; bv[3] = (bf16)wv[i][3];
      int kb = (kc * 8) ^ ((row & 7) << 4);
      *(bf16x4*)(ldsB + row * 128 + kb) = bv;
    }
    __syncthreads();
#pragma unroll
    for (int ks = 0; ks < 2; ++ks) {
      bf16x8 af[TM], bfr[TN];
      int kbb = ks * 64 + hi * 16;
#pragma unroll
      for (int m = 0; m < TM; ++m) {
        int row = wr * (BM / 2) + m * 16 + lo;
        af[m] = *(const bf16x8*)(ldsA + row * 128 + (kbb ^ ((row & 7) << 4)));
      }
#pragma unroll
      for (int n = 0; n < TN; ++n) {
        int row = wc * (BN / 2) + n * 16 + lo;
        bfr[n] = *(const bf16x8*)(ldsB + row * 128 + (kbb ^ ((row & 7) << 4)));
      }
#pragma unroll
      for (int m = 0; m < TM; ++m)
#pragma unroll
        for (int n = 0; n < TN; ++n)
          acc[m][n] = mfma16(af[m], bfr[n], acc[m][n]);
    }
    __syncthreads();
  }
#pragma unroll
  for (int m = 0; m < TM; ++m) {
    int gmb = m0 + wr * (BM / 2) + m * 16 + hi * 4;
#pragma unroll
    for (int n = 0; n < TN; ++n) {
      int gn = n0 + wc * (BN / 2) + n * 16 + lo;
#pragma unroll
      for (int r = 0; r < 4; ++r) {
        float v = acc[m][n][r];
        if (EPI == EPI_STORE) {
          C[(size_t)(gmb + r) * ldc + gn] = v;
        } else if (EPI == EPI_ADD) {
          C[(size_t)(gmb + r) * ldc + gn] += v;
        } else {
          float pv = __shfl_xor(v, 1);
          if (!(lane & 1)) {
            float g2 = fmaxf(v, 0.f);
            Cb[(size_t)(gmb + r) * (W13_N / 2) + (gn >> 1)] = (bf16)(g2 * g2 * pv);
          }
        }
      }
    }
  }
}

// ---------------- GEMM (mid): both A and W bf16, global_load_lds staged ----------------
template<int BM, int BN, int EPI>
__global__ __launch_bounds__(256) void gemm_bb(const bf16* __restrict__ A,
                                               const bf16* __restrict__ W,
                                               float* __restrict__ C, bf16* __restrict__ Cb,
                                               int K, int ldc) {
  constexpr int BK = 64;
  __shared__ __align__(16) char lds[(BM + BN) * BK * 2];
  char* ldsA = lds;
  char* ldsB = lds + BM * BK * 2;
  const int t = threadIdx.x;
  int mtile, ntile;
  xcd_remap(gridDim.x, gridDim.y, mtile, ntile);
  const int m0 = mtile * BM, n0 = ntile * BN;

  const int wid = t >> 6, lane = t & 63;
  const int lo = lane & 15, hi = lane >> 4;
  const int wr = wid >> 1, wc = wid & 1;
  constexpr int TM = BM / 32, TN = BN / 32;
  constexpr int PA = BM / 32, PB = BN / 32;

  f32x4 acc[TM][TN];
#pragma unroll
  for (int m = 0; m < TM; ++m)
#pragma unroll
    for (int n = 0; n < TN; ++n) acc[m][n] = (f32x4){0.f, 0.f, 0.f, 0.f};

  const int prow = t >> 3;
  const int psrcb = (t & 7) * 16;
  const int nk = K / BK;
  for (int kt = 0; kt < nk; ++kt) {
    const int k0 = kt * BK;
#pragma unroll
    for (int i = 0; i < PA; ++i) {
      int row = i * 32 + prow;
      int srcb = psrcb ^ ((row & 7) << 4);
      const bf16* g = A + (size_t)(m0 + row) * K + k0 + (srcb >> 1);
      __builtin_amdgcn_global_load_lds((const AS1 void*)g,
                                       (AS3 void*)(ldsA + i * 4096 + wid * 1024), 16, 0, 0);
    }
#pragma unroll
    for (int i = 0; i < PB; ++i) {
      int row = i * 32 + prow;
      int srcb = psrcb ^ ((row & 7) << 4);
      const bf16* g = W + (size_t)(n0 + row) * K + k0 + (srcb >> 1);
      __builtin_amdgcn_global_load_lds((const AS1 void*)g,
                                       (AS3 void*)(ldsB + i * 4096 + wid * 1024), 16, 0, 0);
    }
    __syncthreads();
#pragma unroll
    for (int ks = 0; ks < 2; ++ks) {
      bf16x8 af[TM], bfr[TN];
      int kbb = ks * 64 + hi * 16;
#pragma unroll
      for (int m = 0; m < TM; ++m) {
        int row = wr * (BM / 2) + m * 16 + lo;
        af[m] = *(const bf16x8*)(ldsA + row * 128 + (kbb ^ ((row & 7) << 4)));
      }
#pragma unroll
      for (int n = 0; n < TN; ++n) {
        int row = wc * (BN / 2) + n * 16 + lo;
        bfr[n] = *(const bf16x8*)(ldsB + row * 128 + (kbb ^ ((row & 7) << 4)));
      }
#pragma unroll
      for (int m = 0; m < TM; ++m)
#pragma unroll
        for (int n = 0; n < TN; ++n)
          acc[m][n] = mfma16(af[m], bfr[n], acc[m][n]);
    }
    __syncthreads();
  }
#pragma unroll
  for (int m = 0; m < TM; ++m) {
    int gmb = m0 + wr * (BM / 2) + m * 16 + hi * 4;
#pragma unroll
    for (int n = 0; n < TN; ++n) {
      int gn = n0 + wc * (BN / 2) + n * 16 + lo;
#pragma unroll
      for (int r = 0; r < 4; ++r) {
        float v = acc[m][n][r];
        if (EPI == EPI_STORE) {
          C[(size_t)(gmb + r) * ldc + gn] = v;
        } else if (EPI == EPI_ADD) {
          C[(size_t)(gmb + r) * ldc + gn] += v;
        } else {
          float pv = __shfl_xor(v, 1);
          if (!(lane & 1)) {
            float g2 = fmaxf(v, 0.f);
            Cb[(size_t)(gmb + r) * (W13_N / 2) + (gn >> 1)] = (bf16)(g2 * g2 * pv);
          }
        }
      }
    }
  }
}

// ---------------- GEMM (big, fused fp32-W): 256x256, 8 waves, 4-phase interleave ----------------
// Quadrant <-> LDS storage-half mapping (fixes round-5/6 race class): phase mh
// selects A half, nh selects B half; wave position folds into the row index.
// Per tile t (reads buf[t&1], stages t+1 into buf^1):
//  P0: BWRITE B1(t) | read A0,B0 | stage A0' + BLOAD B0'regs | MFMA Q00
//  P1: read B1 (A frags persist)                             | MFMA Q01
//  P2: read A1 | stage A1' + BLOAD B1'regs                   | MFMA Q11
//  P3: read B0 again | BWRITE B0'                            | MFMA Q10
// All vm ordering is implicit: each BWRITE's reg dependency emits a counted
// vmcnt that also retires the paired (older) global_load_lds. 1 barrier/phase.
template<int EPI>
__global__ __launch_bounds__(512, 1) void gemm_4p(const bf16* __restrict__ A,
                                                  const float* __restrict__ W,
                                                  float* __restrict__ C, bf16* __restrict__ Cb,
                                                  int K, int ldc) {
  extern __shared__ __align__(16) char lds[];
  char* ldsA = lds;            // [2 buf][2 half][128 rows][128 B] = 64 KB
  char* ldsB = lds + 65536;
  const int t = threadIdx.x;
  int mtile, ntile;
  xcd_remap(gridDim.x, gridDim.y, mtile, ntile);
  const int m0 = mtile * 256, n0 = ntile * 256;
  const int wid = t >> 6, lane = t & 63;
  const int lo = lane & 15, hi = lane >> 4;
  const int wr = wid >> 2, wc = wid & 3;

  f32x4 acc[8][4];
#pragma unroll
  for (int f = 0; f < 8; ++f)
#pragma unroll
    for (int g = 0; g < 4; ++g) acc[f][g] = (f32x4){0.f, 0.f, 0.f, 0.f};

  const int prow = t >> 3;
  const int pcol = (t & 7) * 16;

  auto STAGEA = [&](int h, int kt2) {
    char* dst = ldsA + (kt2 & 1) * 32768 + h * 16384;
    const int k0 = kt2 * 64;
#pragma unroll
    for (int i = 0; i < 2; ++i) {
      int row = i * 64 + prow;
      int srcb = pcol ^ ((row & 7) << 4);
      const bf16* g = A + (size_t)(m0 + h * 128 + row) * K + k0 + (srcb >> 1);
      __builtin_amdgcn_global_load_lds((const AS1 void*)g,
          (AS3 void*)(dst + i * 8192 + wid * 1024), 16, 0, 0);
    }
  };

  f32x4 breg0[2][2], breg1[2][2];
  auto BLOADH = [&](f32x4 (&br)[2][2], int h, int kt2) {
#pragma unroll
    for (int i = 0; i < 2; ++i) {
      int c = t + i * 512;
      int row = c >> 3, kc = c & 7;
      const float* g = W + (size_t)(n0 + h * 128 + row) * K + kt2 * 64 + kc * 8;
      br[i][0] = *(const f32x4*)(g);
      br[i][1] = *(const f32x4*)(g + 4);
    }
  };
  auto BWRITEH = [&](f32x4 (&br)[2][2], int h, int kt2) {
#pragma unroll
    for (int i = 0; i < 2; ++i) {
      int c = t + i * 512;
      int row = c >> 3, kc = c & 7;
      bf16x8 bv;
#pragma unroll
      for (int e = 0; e < 4; ++e) {
        bv[e]     = (bf16)br[i][0][e];
        bv[4 + e] = (bf16)br[i][1][e];
      }
      *(bf16x8*)(ldsB + (kt2 & 1) * 32768 + h * 16384 + row * 128 +
                 ((kc * 16) ^ ((row & 7) << 4))) = bv;
    }
  };

  // half selected by PHASE (mh/nh); wave position inside the half.
  auto LDA = [&](int buf, int mh, int i, int ks) -> bf16x8 {
    int row = wr * 64 + i * 16 + lo;
    return *(const bf16x8*)(ldsA + buf * 32768 + mh * 16384 + row * 128 +
                            ((ks * 64 + hi * 16) ^ ((row & 7) << 4)));
  };
  auto LDB = [&](int buf, int nh, int j, int ks) -> bf16x8 {
    int row = wc * 32 + j * 16 + lo;
    return *(const bf16x8*)(ldsB + buf * 32768 + nh * 16384 + row * 128 +
                            ((ks * 64 + hi * 16) ^ ((row & 7) << 4)));
  };

  const int nk = K / 64;
  bf16x8 a[4][2], b[2][2];

  // prologue: tile 0 -> buf 0.  A via gload_lds; B0 via reg+write; B1 regs kept.
  STAGEA(0, 0);
  STAGEA(1, 0);
  __builtin_amdgcn_sched_barrier(0);
  BLOADH(breg0, 0, 0);
  BWRITEH(breg0, 0, 0);          // implicit vmcnt: waits breg0, retires A stages
  __builtin_amdgcn_sched_barrier(0);
  BLOADH(breg1, 1, 0);           // tile0 B1 -> regs (written at tile0 P0)
  asm volatile("s_waitcnt lgkmcnt(0)" ::: "memory");
  __builtin_amdgcn_s_barrier();

  for (int kt = 0; kt < nk; ++kt) {
    const int buf = kt & 1;
    const bool more = (kt + 1) < nk;
    // ---- P0: Q(0,0)
    BWRITEH(breg1, 1, kt);       // B1 of THIS tile (implicit wait retires A1 stage)
#pragma unroll
    for (int i = 0; i < 4; ++i) { a[i][0] = LDA(buf, 0, i, 0); a[i][1] = LDA(buf, 0, i, 1); }
#pragma unroll
    for (int j = 0; j < 2; ++j) { b[j][0] = LDB(buf, 0, j, 0); b[j][1] = LDB(buf, 0, j, 1); }
    if (more) {
      STAGEA(0, kt + 1);
      __builtin_amdgcn_sched_barrier(0);
      BLOADH(breg0, 0, kt + 1);
    }
    asm volatile("s_waitcnt lgkmcnt(0)" ::: "memory");
    __builtin_amdgcn_sched_barrier(0);
    __builtin_amdgcn_s_setprio(1);
#pragma unroll
    for (int i = 0; i < 4; ++i)
#pragma unroll
      for (int j = 0; j < 2; ++j) {
        acc[i][j] = mfma16(a[i][0], b[j][0], acc[i][j]);
        acc[i][j] = mfma16(a[i][1], b[j][1], acc[i][j]);
      }
    __builtin_amdgcn_s_setprio(0);
    __builtin_amdgcn_s_barrier();
    // ---- P1: Q(0,1)  (A frags persist; read B1)
#pragma unroll
    for (int j = 0; j < 2; ++j) { b[j][0] = LDB(buf, 1, j, 0); b[j][1] = LDB(buf, 1, j, 1); }
    asm volatile("s_waitcnt lgkmcnt(0)" ::: "memory");
    __builtin_amdgcn_sched_barrier(0);
    __builtin_amdgcn_s_setprio(1);
#pragma unroll
    for (int i = 0; i < 4; ++i)
#pragma unroll
      for (int j = 0; j < 2; ++j) {
        acc[i][2 + j] = mfma16(a[i][0], b[j][0], acc[i][2 + j]);
        acc[i][2 + j] = mfma16(a[i][1], b[j][1], acc[i][2 + j]);
      }
    __builtin_amdgcn_s_setprio(0);
    __builtin_amdgcn_s_barrier();
    // ---- P2: Q(1,1)  (B frags persist; read A1)
#pragma unroll
    for (int i = 0; i < 4; ++i) { a[i][0] = LDA(buf, 1, i, 0); a[i][1] = LDA(buf, 1, i, 1); }
    if (more) {
      STAGEA(1, kt + 1);
      __builtin_amdgcn_sched_barrier(0);
      BLOADH(breg1, 1, kt + 1);
    }
    asm volatile("s_waitcnt lgkmcnt(0)" ::: "memory");
    __builtin_amdgcn_sched_barrier(0);
    __builtin_amdgcn_s_setprio(1);
#pragma unroll
    for (int i = 0; i < 4; ++i)
#pragma unroll
      for (int j = 0; j < 2; ++j) {
        acc[4 + i][2 + j] = mfma16(a[i][0], b[j][0], acc[4 + i][2 + j]);
        acc[4 + i][2 + j] = mfma16(a[i][1], b[j][1], acc[4 + i][2 + j]);
      }
    __builtin_amdgcn_s_setprio(0);
    __builtin_amdgcn_s_barrier();
    // ---- P3: Q(1,0)  (re-read B0; write B0' for next tile)
#pragma unroll
    for (int j = 0; j < 2; ++j) { b[j][0] = LDB(buf, 0, j, 0); b[j][1] = LDB(buf, 0, j, 1); }
    if (more) BWRITEH(breg0, 0, kt + 1);   // implicit wait retires A0' stage too
    asm volatile("s_waitcnt lgkmcnt(0)" ::: "memory");
    __builtin_amdgcn_sched_barrier(0);
    __builtin_amdgcn_s_setprio(1);
#pragma unroll
    for (int i = 0; i < 4; ++i)
#pragma unroll
      for (int j = 0; j < 2; ++j) {
        acc[4 + i][j] = mfma16(a[i][0], b[j][0], acc[4 + i][j]);
        acc[4 + i][j] = mfma16(a[i][1], b[j][1], acc[4 + i][j]);
      }
    __builtin_amdgcn_s_setprio(0);
    __builtin_amdgcn_s_barrier();
  }
  // epilogue (new index mapping: f=mh*4+i, g=nh*2+j)
#pragma unroll
  for (int f = 0; f < 8; ++f) {
    int gmb = m0 + (f >> 2) * 128 + wr * 64 + (f & 3) * 16 + hi * 4;
#pragma unroll
    for (int g = 0; g < 4; ++g) {
      int gn = n0 + (g >> 1) * 128 + wc * 32 + (g & 1) * 16 + lo;
#pragma unroll
      for (int r = 0; r < 4; ++r) {
        float v = acc[f][g][r];
        if (EPI == EPI_STORE) {
          C[(size_t)(gmb + r) * ldc + gn] = v;
        } else if (EPI == EPI_ADD) {
          C[(size_t)(gmb + r) * ldc + gn] += v;
        } else {
          float pv = __shfl_xor(v, 1);
          if (!(lane & 1)) {
            float g2 = fmaxf(v, 0.f);
            Cb[(size_t)(gmb + r) * (W13_N / 2) + (gn >> 1)] = (bf16)(g2 * g2 * pv);
          }
        }
      }
    }
  }
}

// ---------------- launch ----------------
extern "C" void kernel_launch(void* const* d_in, const int* in_sizes, int n_in,
                              void* d_out, int out_size, void* d_ws, size_t ws_size,
                              hipStream_t stream) {
  const int* tokens = (const int*)d_in[0];
  const float* img_feats = (const float*)d_in[1];
  const float* freqs = (const float*)d_in[2];
  const float* freqs2 = (const float*)d_in[3];
  const float* tok_emb = (const float*)d_in[4];
  const float* img_proj_w = (const float*)d_in[5];
  const float* wqkv = (const float*)d_in[6];
  const float* wo = (const float*)d_in[7];
  const float* sinks = (const float*)d_in[8];
  const float* w13 = (const float*)d_in[9];
  const float* w2 = (const float*)d_in[10];
  const float* norm_w = (const float*)d_in[11];
  const float* output_w = (const float*)d_in[12];
  float* out = (float*)d_out;

  char* ws = (char*)d_ws;
  float* x = (float*)ws;   ws += (size_t)S_LEN * DIM * 4;
  bf16* h = (bf16*)ws;     ws += (size_t)S_LEN * DIM * 2;
  float* qkv = (float*)ws; ws += (size_t)S_LEN * QKV_N * 4;
  bf16* qb = (bf16*)ws;    ws += (size_t)NH * S_LEN * HD * 2;
  bf16* kb = (bf16*)ws;    ws += (size_t)NKVH * S_LEN * HD * 2;
  bf16* vtb = (bf16*)ws;   ws += (size_t)NKVH * HD * S_LEN * 2;
  bf16* ao = (bf16*)ws;    ws += (size_t)S_LEN * DIM * 2;
  bf16* act = (bf16*)ws;   ws += (size_t)S_LEN * HID * 2;
  bf16* imgb = (bf16*)ws;  ws += (size_t)NIMG * IMG_K * 2;
  const size_t n_wqkv = (size_t)2 * QKV_N * DIM;
  const size_t n_wo   = (size_t)2 * DIM * (NH * HD);
  const size_t n_w2   = (size_t)2 * DIM * HID;
  bf16* wqkvb = (bf16*)ws; ws += n_wqkv * 2;
  bf16* wob   = (bf16*)ws; ws += n_wo * 2;
  bf16* w2b   = (bf16*)ws; ws += n_w2 * 2;
  const bool bf16_path = ((size_t)(ws - (char*)d_ws) <= ws_size);

  bool big_ok = false;
  {
    hipError_t e1 = hipFuncSetAttribute((const void*)&gemm_4p<EPI_STORE>,
                                        hipFuncAttributeMaxDynamicSharedMemorySize, 131072);
    hipError_t e2 = hipFuncSetAttribute((const void*)&gemm_4p<EPI_ACT>,
                                        hipFuncAttributeMaxDynamicSharedMemorySize, 131072);
    if (e1 == hipSuccess && e2 == hipSuccess) {
      hipFuncAttributes fa1{}, fa2{};
      if (hipFuncGetAttributes(&fa1, (const void*)&gemm_4p<EPI_STORE>) == hipSuccess &&
          hipFuncGetAttributes(&fa2, (const void*)&gemm_4p<EPI_ACT>) == hipSuccess)
        big_ok = fa1.maxDynamicSharedSizeBytes >= 131072 &&
                 fa2.maxDynamicSharedSizeBytes >= 131072;
    }
  }

  embed_kernel<<<S_LEN, 256, 0, stream>>>(tokens, tok_emb, x);
  cvt_kernel<<<(NIMG * IMG_K + 255) / 256, 256, 0, stream>>>(img_feats, imgb, NIMG * IMG_K);
  gemm_bt<64, 128, EPI_STORE, 0><<<dim3(NIMG / 64, DIM / 128), 256, 0, stream>>>(
      imgb, img_proj_w, x + DIM, nullptr, NIMG, DIM, IMG_K, DIM);

  if (bf16_path) {
    cvt4_kernel<<<(int)(n_wqkv / 4 + 255) / 256, 256, 0, stream>>>(wqkv, wqkvb, (int)(n_wqkv / 4));
    cvt4_kernel<<<(int)(n_wo / 4 + 255) / 256, 256, 0, stream>>>(wo, wob, (int)(n_wo / 4));
    cvt4_kernel<<<(int)(n_w2 / 4 + 255) / 256, 256, 0, stream>>>(w2, w2b, (int)(n_w2 / 4));
  }

  for (int i = 0; i < 2; ++i) {
    rmsnorm_kernel<0><<<S_LEN, 256, 0, stream>>>(x, nullptr, h);
    if (bf16_path) {
      gemm_bb<64, 128, EPI_STORE><<<dim3(S_LEN / 64, QKV_N / 128), 256, 0, stream>>>(
          h, wqkvb + (size_t)i * QKV_N * DIM, qkv, nullptr, DIM, QKV_N);
    } else {
      gemm_bt<64, 128, EPI_STORE, 1><<<dim3(S_LEN / 64, QKV_N / 128), 256, 0, stream>>>(
          h, wqkv + (size_t)i * QKV_N * DIM, qkv, nullptr, S_LEN, QKV_N, DIM, QKV_N);
    }
    qkvpost_kernel<<<S_LEN, 256, 0, stream>>>(qkv, freqs, freqs2, qb, kb, vtb);
    attn_kernel<<<dim3(S_LEN / 16, NH), 256, 0, stream>>>(qb, kb, vtb, sinks + i * NH, ao);
    if (bf16_path) {
      gemm_bb<64, 128, EPI_ADD><<<dim3(S_LEN / 64, DIM / 128), 256, 0, stream>>>(
          ao, wob + (size_t)i * DIM * DIM, x, nullptr, DIM, DIM);
    } else {
      gemm_bt<64, 128, EPI_ADD, 1><<<dim3(S_LEN / 64, DIM / 128), 256, 0, stream>>>(
          ao, wo + (size_t)i * DIM * DIM, x, nullptr, S_LEN, DIM, DIM, DIM);
    }
    rmsnorm_kernel<0><<<S_LEN, 256, 0, stream>>>(x, nullptr, h);
    if (big_ok) {
      gemm_4p<EPI_ACT><<<dim3(S_LEN / 256, W13_N / 256), 512, 131072, stream>>>(
          h, w13 + (size_t)i * W13_N * DIM, nullptr, act, DIM, 0);
    } else {
      gemm_bt<128, 128, EPI_ACT, 1><<<dim3(S_LEN / 128, W13_N / 128), 256, 0, stream>>>(
          h, w13 + (size_t)i * W13_N * DIM, nullptr, act, S_LEN, W13_N, DIM, 0);
    }
    if (bf16_path) {
      gemm_bb<64, 128, EPI_ADD><<<dim3(S_LEN / 64, DIM / 128), 256, 0, stream>>>(
          act, w2b + (size_t)i * DIM * HID, x, nullptr, HID, DIM);
    } else {
      gemm_bt<64, 128, EPI_ADD, 1><<<dim3(S_LEN / 64, DIM / 128), 256, 0, stream>>>(
          act, w2 + (size_t)i * DIM * HID, x, nullptr, S_LEN, DIM, HID, DIM);
    }
  }
  rmsnorm_kernel<1><<<S_LEN, 256, 0, stream>>>(x, norm_w, h);
  if (big_ok) {
    gemm_4p<EPI_STORE><<<dim3(S_LEN / 256, VOCAB / 256), 512, 131072, stream>>>(
        h, output_w, out, nullptr, DIM, VOCAB);
  } else {
    gemm_bt<128, 128, EPI_STORE, 1><<<dim3(S_LEN / 128, VOCAB / 128), 256, 0, stream>>>(
        h, output_w, out, nullptr, S_LEN, VOCAB, DIM, VOCAB);
  }
}

// Round 13
// 1032.790 us; speedup vs baseline: 1.0322x; 1.0322x over previous
//
#include <hip/hip_runtime.h>

typedef __bf16 bf16;
typedef bf16 bf16x8 __attribute__((ext_vector_type(8)));
typedef bf16 bf16x4 __attribute__((ext_vector_type(4)));
typedef bf16 bf16x2 __attribute__((ext_vector_type(2)));
typedef float f32x4 __attribute__((ext_vector_type(4)));
typedef float f32x2 __attribute__((ext_vector_type(2)));

#define S_LEN 1024
#define DIM 2048
#define NH 16
#define NKVH 4
#define HD 128
#define HID 8192
#define VOCAB 32000
#define QKV_N 3072
#define W13_N 16384
#define IMG_K 1176
#define NIMG 256

#define AS1 __attribute__((address_space(1)))
#define AS3 __attribute__((address_space(3)))

__device__ inline f32x4 mfma16(bf16x8 a, bf16x8 b, f32x4 c) {
  return __builtin_amdgcn_mfma_f32_16x16x32_bf16(a, b, c, 0, 0, 0);
}

// ---------------- embed ----------------
__global__ void embed_kernel(const int* __restrict__ tok, const float* __restrict__ emb,
                             float* __restrict__ x) {
  int s = blockIdx.x, t = threadIdx.x;
  int id = tok[s];
  const float* er = emb + (size_t)id * DIM;
  float* xr = x + (size_t)s * DIM;
  *(f32x4*)(xr + t * 8)     = *(const f32x4*)(er + t * 8);
  *(f32x4*)(xr + t * 8 + 4) = *(const f32x4*)(er + t * 8 + 4);
}

// ---------------- fp32 -> bf16 converts ----------------
__global__ void cvt_kernel(const float* __restrict__ in, bf16* __restrict__ o, int n) {
  int i = blockIdx.x * 256 + threadIdx.x;
  if (i < n) o[i] = (bf16)in[i];
}
__global__ void cvt4_kernel(const float* __restrict__ in, bf16* __restrict__ o, int n4) {
  int i = blockIdx.x * 256 + threadIdx.x;
  if (i < n4) {
    f32x4 v = *(const f32x4*)(in + (size_t)i * 4);
    bf16x4 b;
    b[0] = (bf16)v[0]; b[1] = (bf16)v[1]; b[2] = (bf16)v[2]; b[3] = (bf16)v[3];
    *(bf16x4*)(o + (size_t)i * 4) = b;
  }
}

// ---------------- rmsnorm (x fp32 -> bf16) ----------------
template<int USE_W>
__global__ void rmsnorm_kernel(const float* __restrict__ x, const float* __restrict__ w,
                               bf16* __restrict__ o) {
  const int row = blockIdx.x, t = threadIdx.x;
  const float* xr = x + (size_t)row * DIM;
  f32x4 a = *(const f32x4*)(xr + t * 8);
  f32x4 b = *(const f32x4*)(xr + t * 8 + 4);
  float ss = a[0]*a[0] + a[1]*a[1] + a[2]*a[2] + a[3]*a[3]
           + b[0]*b[0] + b[1]*b[1] + b[2]*b[2] + b[3]*b[3];
#pragma unroll
  for (int off = 1; off < 64; off <<= 1) ss += __shfl_xor(ss, off);
  __shared__ float red[4];
  if ((t & 63) == 0) red[t >> 6] = ss;
  __syncthreads();
  ss = red[0] + red[1] + red[2] + red[3];
  float r = rsqrtf(ss * (1.0f / DIM) + 1e-6f);
  bf16x8 ov;
  if (USE_W) {
    f32x4 w1 = *(const f32x4*)(w + t * 8);
    f32x4 w2v = *(const f32x4*)(w + t * 8 + 4);
    ov[0] = (bf16)(a[0]*r*w1[0]); ov[1] = (bf16)(a[1]*r*w1[1]);
    ov[2] = (bf16)(a[2]*r*w1[2]); ov[3] = (bf16)(a[3]*r*w1[3]);
    ov[4] = (bf16)(b[0]*r*w2v[0]); ov[5] = (bf16)(b[1]*r*w2v[1]);
    ov[6] = (bf16)(b[2]*r*w2v[2]); ov[7] = (bf16)(b[3]*r*w2v[3]);
  } else {
    ov[0] = (bf16)(a[0]*r); ov[1] = (bf16)(a[1]*r);
    ov[2] = (bf16)(a[2]*r); ov[3] = (bf16)(a[3]*r);
    ov[4] = (bf16)(b[0]*r); ov[5] = (bf16)(b[1]*r);
    ov[6] = (bf16)(b[2]*r); ov[7] = (bf16)(b[3]*r);
  }
  *(bf16x8*)(o + (size_t)row * DIM + t * 8) = ov;
}

// ---------------- qkv post: per-head rms + rope, write q/k/vT bf16 ----------------
__global__ void qkvpost_kernel(const float* __restrict__ qkv, const float* __restrict__ f1,
                               const float* __restrict__ f2, bf16* __restrict__ qb,
                               bf16* __restrict__ kb, bf16* __restrict__ vtb) {
  int s = blockIdx.x, t = threadIdx.x;
  __shared__ float cs[64], sn[64];
  if (t < 64) {
    float ang = (t < 32) ? f1[(size_t)s * 32 + t] : f2[(size_t)s * 32 + (t - 32)];
    cs[t] = cosf(ang);
    sn[t] = sinf(ang);
  }
  __syncthreads();
  int w = t >> 6, lane = t & 63;
  for (int hh = w; hh < 24; hh += 4) {
    const float* base = qkv + (size_t)s * QKV_N + hh * HD;
    f32x2 e = *(const f32x2*)(base + lane * 2);
    if (hh < 20) {
      float ssum = e[0]*e[0] + e[1]*e[1];
#pragma unroll
      for (int off = 1; off < 64; off <<= 1) ssum += __shfl_xor(ssum, off);
      float r = rsqrtf(ssum * (1.0f / HD) + 1e-6f);
      float x1 = e[0] * r, x2 = e[1] * r;
      float c = cs[lane], s2 = sn[lane];
      bf16x2 ov;
      ov[0] = (bf16)(x1 * c - x2 * s2);
      ov[1] = (bf16)(x1 * s2 + x2 * c);
      if (hh < 16)
        *(bf16x2*)(qb + ((size_t)hh * S_LEN + s) * HD + lane * 2) = ov;
      else
        *(bf16x2*)(kb + ((size_t)(hh - 16) * S_LEN + s) * HD + lane * 2) = ov;
    } else {
      int kv = hh - 20;
      vtb[((size_t)kv * HD + lane * 2) * S_LEN + s]     = (bf16)e[0];
      vtb[((size_t)kv * HD + lane * 2 + 1) * S_LEN + s] = (bf16)e[1];
    }
  }
}

// ---------------- flash attention, KV-split across 4 waves ----------------
__global__ __launch_bounds__(256) void attn_kernel(const bf16* __restrict__ qb,
                                                   const bf16* __restrict__ kb,
                                                   const bf16* __restrict__ vtb,
                                                   const float* __restrict__ sinks,
                                                   bf16* __restrict__ out) {
  const int h = blockIdx.y, qs = blockIdx.x;
  const int w = threadIdx.x >> 6, lane = threadIdx.x & 63;
  const int lo = lane & 15, hi = lane >> 4;
  const int q0 = qs * 16;
  const int q = q0 + lo;
  const int kvh = h >> 2;
  const bf16* Q = qb + (size_t)h * S_LEN * HD;
  const bf16* Kp = kb + (size_t)kvh * S_LEN * HD;
  const bf16* Vt = vtb + (size_t)kvh * HD * S_LEN;
  const float scale = 0.08838834764831845f;

  __shared__ float accS[4][64 * 36];
  __shared__ float mS[4][16], lS[4][16];

  bf16x8 qf[4];
#pragma unroll
  for (int ks = 0; ks < 4; ++ks)
    qf[ks] = *(const bf16x8*)(Q + (size_t)q * HD + ks * 32 + hi * 8);

  f32x4 accT[8];
#pragma unroll
  for (int i = 0; i < 8; ++i) accT[i] = (f32x4){0.f, 0.f, 0.f, 0.f};
  float mrow = -3e38f, lrow = 0.f;

  const int nt = (q0 + 15) / 32 + 1;
  for (int tile = w; tile < nt; tile += 4) {
    const int kv0 = tile * 32;
    f32x4 st0 = (f32x4){0.f,0.f,0.f,0.f}, st1 = (f32x4){0.f,0.f,0.f,0.f};
#pragma unroll
    for (int ks = 0; ks < 4; ++ks) {
      const bf16* kbase = Kp + (size_t)(kv0 + lo) * HD + ks * 32 + hi * 8;
      bf16x8 k0f = *(const bf16x8*)(kbase);
      bf16x8 k1f = *(const bf16x8*)(kbase + 16 * HD);
      st0 = mfma16(k0f, qf[ks], st0);
      st1 = mfma16(k1f, qf[ks], st1);
    }
    float p[2][4];
    float pmax = -3e38f;
#pragma unroll
    for (int r = 0; r < 4; ++r) {
      int kvg0 = kv0 + hi * 4 + r;
      float v0 = (kvg0 <= q) ? st0[r] * scale : -3e38f;
      int kvg1 = kvg0 + 16;
      float v1 = (kvg1 <= q) ? st1[r] * scale : -3e38f;
      p[0][r] = v0; p[1][r] = v1;
      pmax = fmaxf(pmax, fmaxf(v0, v1));
    }
    pmax = fmaxf(pmax, __shfl_xor(pmax, 16));
    pmax = fmaxf(pmax, __shfl_xor(pmax, 32));
    float mnew = fmaxf(mrow, pmax);
    float alpha = __expf(mrow - mnew);
    float ps = 0.f;
#pragma unroll
    for (int f = 0; f < 2; ++f)
#pragma unroll
      for (int r = 0; r < 4; ++r) {
        float e = __expf(p[f][r] - mnew);
        p[f][r] = e;
        ps += e;
      }
    ps += __shfl_xor(ps, 16);
    ps += __shfl_xor(ps, 32);
    lrow = lrow * alpha + ps;
    mrow = mnew;
#pragma unroll
    for (int fd = 0; fd < 8; ++fd) {
      accT[fd][0] *= alpha; accT[fd][1] *= alpha;
      accT[fd][2] *= alpha; accT[fd][3] *= alpha;
    }
    bf16x8 pb;
#pragma unroll
    for (int j = 0; j < 8; ++j) {
      int src = ((j >> 2) + 2 * (hi & 1)) * 16 + lo;
      float v0 = __shfl(p[0][j & 3], src);
      float v1 = __shfl(p[1][j & 3], src);
      pb[j] = (bf16)((hi >= 2) ? v1 : v0);
    }
#pragma unroll
    for (int fd = 0; fd < 8; ++fd) {
      bf16x8 vf = *(const bf16x8*)(Vt + (size_t)(fd * 16 + lo) * S_LEN + kv0 + hi * 8);
      accT[fd] = mfma16(vf, pb, accT[fd]);
    }
  }
  if (hi == 0) { mS[w][lo] = mrow; lS[w][lo] = lrow; }
  float* as = &accS[w][lane * 36];
#pragma unroll
  for (int fd = 0; fd < 8; ++fd) *(f32x4*)(as + fd * 4) = accT[fd];
  __syncthreads();
  float m0 = mS[0][lo], m1 = mS[1][lo], m2 = mS[2][lo], m3 = mS[3][lo];
  float mstar = fmaxf(fmaxf(m0, m1), fmaxf(m2, m3));
  float e0 = __expf(m0 - mstar), e1 = __expf(m1 - mstar);
  float e2 = __expf(m2 - mstar), e3 = __expf(m3 - mstar);
  float lstar = lS[0][lo]*e0 + lS[1][lo]*e1 + lS[2][lo]*e2 + lS[3][lo]*e3;
  float lse = mstar + __logf(lstar);
  float ssig = 1.f / (1.f + __expf(sinks[h] - lse));
  float sc = ssig / lstar;
#pragma unroll
  for (int f2 = 0; f2 < 2; ++f2) {
    int fd = w * 2 + f2;
    f32x4 a0 = *(const f32x4*)&accS[0][lane * 36 + fd * 4];
    f32x4 a1 = *(const f32x4*)&accS[1][lane * 36 + fd * 4];
    f32x4 a2 = *(const f32x4*)&accS[2][lane * 36 + fd * 4];
    f32x4 a3 = *(const f32x4*)&accS[3][lane * 36 + fd * 4];
#pragma unroll
    for (int r = 0; r < 4; ++r) {
      float o = a0[r]*e0 + a1[r]*e1 + a2[r]*e2 + a3[r]*e3;
      out[(size_t)q * DIM + h * HD + fd * 16 + hi * 4 + r] = (bf16)(o * sc);
    }
  }
}

// ---------------- XCD-aware (m,n) remap helper ----------------
__device__ inline void xcd_remap(int ntm, int ntn, int& mtile, int& ntile) {
  const int flat = blockIdx.x + ntm * blockIdx.y;
  const int chunk = ntm * 8;
  const int gfull = ntn >> 3;
  const int g = flat / chunk;
  if (g < gfull) {
    int rem = flat - g * chunk;
    ntile = g * 8 + (rem & 7);
    mtile = rem >> 3;
  } else {
    int rem = flat - gfull * chunk;
    int nrem = ntn - gfull * 8;
    ntile = gfull * 8 + rem % nrem;
    mtile = rem / nrem;
  }
}

enum { EPI_STORE = 0, EPI_ADD = 1, EPI_ACT = 2 };

// ---------------- GEMM (fp32-W / img / small): W fp32, reg-staged ----------------
template<int BM, int BN, int EPI, int GL>
__global__ void gemm_bt(const bf16* __restrict__ A, const float* __restrict__ W,
                        float* __restrict__ C, bf16* __restrict__ Cb,
                        int M, int N, int K, int ldc) {
  constexpr int BK = 64;
  __shared__ __align__(16) char lds[(BM + BN) * BK * 2];
  char* ldsA = lds;
  char* ldsB = lds + BM * BK * 2;
  const int t = threadIdx.x;
  int mtile, ntile;
  xcd_remap(gridDim.x, gridDim.y, mtile, ntile);
  const int m0 = mtile * BM, n0 = ntile * BN;

  const int wid = t >> 6, lane = t & 63;
  const int lo = lane & 15, hi = lane >> 4;
  const int wr = wid >> 1, wc = wid & 1;
  constexpr int TM = BM / 32, TN = BN / 32;
  constexpr int NA = BM / 32;
  constexpr int NPASS = BM / 32;
  constexpr int NW = BN / 16;

  f32x4 acc[TM][TN];
#pragma unroll
  for (int m = 0; m < TM; ++m)
#pragma unroll
    for (int n = 0; n < TN; ++n) acc[m][n] = (f32x4){0.f, 0.f, 0.f, 0.f};

  const int nk = (K + BK - 1) / BK;
  for (int kt = 0; kt < nk; ++kt) {
    const int k0 = kt * BK;
    bf16x8 av[NA];
    f32x4 wv[NW];
    if (!GL) {
#pragma unroll
      for (int i = 0; i < NA; ++i) {
        int c = t + i * 256;
        int row = c >> 3, kc = c & 7;
        int kg = k0 + kc * 8;
        bf16x8 z = {};
        av[i] = (kg < K) ? *(const bf16x8*)(A + (size_t)(m0 + row) * K + kg) : z;
      }
    }
#pragma unroll
    for (int i = 0; i < NW; ++i) {
      int c = t + i * 256;
      int row = c >> 4, kc = c & 15;
      int kg = k0 + kc * 4;
      f32x4 z = (f32x4){0.f, 0.f, 0.f, 0.f};
      wv[i] = (kg < K) ? *(const f32x4*)(W + (size_t)(n0 + row) * K + kg) : z;
    }
    __syncthreads();
    if (GL) {
#pragma unroll
      for (int i = 0; i < NPASS; ++i) {
        int row = i * 32 + (t >> 3);
        int srcb = ((t & 7) * 16) ^ ((row & 7) << 4);
        const bf16* g2 = A + (size_t)(m0 + row) * K + k0 + (srcb >> 1);
        char* l = ldsA + i * 4096 + wid * 1024;
        __builtin_amdgcn_global_load_lds((const AS1 void*)g2, (AS3 void*)l, 16, 0, 0);
      }
    } else {
#pragma unroll
      for (int i = 0; i < NA; ++i) {
        int c = t + i * 256;
        int row = c >> 3, kc = c & 7;
        int kb = (kc * 16) ^ ((row & 7) << 4);
        *(bf16x8*)(ldsA + row * 128 + kb) = av[i];
      }
    }
#pragma unroll
    for (int i = 0; i < NW; ++i) {
      int c = t + i * 256;
      int row = c >> 4, kc = c & 15;
      bf16x4 bv;
      bv[0] = (bf16)wv[i][0]; bv[1] = (bf16)wv[i][1];
      bv[2] = (bf16)wv[i][2]; bv[3] = (bf16)wv[i][3];
      int kb = (kc * 8) ^ ((row & 7) << 4);
      *(bf16x4*)(ldsB + row * 128 + kb) = bv;
    }
    __syncthreads();
#pragma unroll
    for (int ks = 0; ks < 2; ++ks) {
      bf16x8 af[TM], bfr[TN];
      int kbb = ks * 64 + hi * 16;
#pragma unroll
      for (int m = 0; m < TM; ++m) {
        int row = wr * (BM / 2) + m * 16 + lo;
        af[m] = *(const bf16x8*)(ldsA + row * 128 + (kbb ^ ((row & 7) << 4)));
      }
#pragma unroll
      for (int n = 0; n < TN; ++n) {
        int row = wc * (BN / 2) + n * 16 + lo;
        bfr[n] = *(const bf16x8*)(ldsB + row * 128 + (kbb ^ ((row & 7) << 4)));
      }
#pragma unroll
      for (int m = 0; m < TM; ++m)
#pragma unroll
        for (int n = 0; n < TN; ++n)
          acc[m][n] = mfma16(af[m], bfr[n], acc[m][n]);
    }
    __syncthreads();
  }
#pragma unroll
  for (int m = 0; m < TM; ++m) {
    int gmb = m0 + wr * (BM / 2) + m * 16 + hi * 4;
#pragma unroll
    for (int n = 0; n < TN; ++n) {
      int gn = n0 + wc * (BN / 2) + n * 16 + lo;
#pragma unroll
      for (int r = 0; r < 4; ++r) {
        float v = acc[m][n][r];
        if (EPI == EPI_STORE) {
          C[(size_t)(gmb + r) * ldc + gn] = v;
        } else if (EPI == EPI_ADD) {
          C[(size_t)(gmb + r) * ldc + gn] += v;
        } else {
          float pv = __shfl_xor(v, 1);
          if (!(lane & 1)) {
            float g2 = fmaxf(v, 0.f);
            Cb[(size_t)(gmb + r) * (W13_N / 2) + (gn >> 1)] = (bf16)(g2 * g2 * pv);
          }
        }
      }
    }
  }
}

// ---------------- GEMM (mid): both A and W bf16, global_load_lds staged ----------------
template<int BM, int BN, int EPI>
__global__ __launch_bounds__(256) void gemm_bb(const bf16* __restrict__ A,
                                               const bf16* __restrict__ W,
                                               float* __restrict__ C, bf16* __restrict__ Cb,
                                               int K, int ldc) {
  constexpr int BK = 64;
  __shared__ __align__(16) char lds[(BM + BN) * BK * 2];
  char* ldsA = lds;
  char* ldsB = lds + BM * BK * 2;
  const int t = threadIdx.x;
  int mtile, ntile;
  xcd_remap(gridDim.x, gridDim.y, mtile, ntile);
  const int m0 = mtile * BM, n0 = ntile * BN;

  const int wid = t >> 6, lane = t & 63;
  const int lo = lane & 15, hi = lane >> 4;
  const int wr = wid >> 1, wc = wid & 1;
  constexpr int TM = BM / 32, TN = BN / 32;
  constexpr int PA = BM / 32, PB = BN / 32;

  f32x4 acc[TM][TN];
#pragma unroll
  for (int m = 0; m < TM; ++m)
#pragma unroll
    for (int n = 0; n < TN; ++n) acc[m][n] = (f32x4){0.f, 0.f, 0.f, 0.f};

  const int prow = t >> 3;
  const int psrcb = (t & 7) * 16;
  const int nk = K / BK;
  for (int kt = 0; kt < nk; ++kt) {
    const int k0 = kt * BK;
#pragma unroll
    for (int i = 0; i < PA; ++i) {
      int row = i * 32 + prow;
      int srcb = psrcb ^ ((row & 7) << 4);
      const bf16* g = A + (size_t)(m0 + row) * K + k0 + (srcb >> 1);
      __builtin_amdgcn_global_load_lds((const AS1 void*)g,
                                       (AS3 void*)(ldsA + i * 4096 + wid * 1024), 16, 0, 0);
    }
#pragma unroll
    for (int i = 0; i < PB; ++i) {
      int row = i * 32 + prow;
      int srcb = psrcb ^ ((row & 7) << 4);
      const bf16* g = W + (size_t)(n0 + row) * K + k0 + (srcb >> 1);
      __builtin_amdgcn_global_load_lds((const AS1 void*)g,
                                       (AS3 void*)(ldsB + i * 4096 + wid * 1024), 16, 0, 0);
    }
    __syncthreads();
#pragma unroll
    for (int ks = 0; ks < 2; ++ks) {
      bf16x8 af[TM], bfr[TN];
      int kbb = ks * 64 + hi * 16;
#pragma unroll
      for (int m = 0; m < TM; ++m) {
        int row = wr * (BM / 2) + m * 16 + lo;
        af[m] = *(const bf16x8*)(ldsA + row * 128 + (kbb ^ ((row & 7) << 4)));
      }
#pragma unroll
      for (int n = 0; n < TN; ++n) {
        int row = wc * (BN / 2) + n * 16 + lo;
        bfr[n] = *(const bf16x8*)(ldsB + row * 128 + (kbb ^ ((row & 7) << 4)));
      }
#pragma unroll
      for (int m = 0; m < TM; ++m)
#pragma unroll
        for (int n = 0; n < TN; ++n)
          acc[m][n] = mfma16(af[m], bfr[n], acc[m][n]);
    }
    __syncthreads();
  }
#pragma unroll
  for (int m = 0; m < TM; ++m) {
    int gmb = m0 + wr * (BM / 2) + m * 16 + hi * 4;
#pragma unroll
    for (int n = 0; n < TN; ++n) {
      int gn = n0 + wc * (BN / 2) + n * 16 + lo;
#pragma unroll
      for (int r = 0; r < 4; ++r) {
        float v = acc[m][n][r];
        if (EPI == EPI_STORE) {
          C[(size_t)(gmb + r) * ldc + gn] = v;
        } else if (EPI == EPI_ADD) {
          C[(size_t)(gmb + r) * ldc + gn] += v;
        } else {
          float pv = __shfl_xor(v, 1);
          if (!(lane & 1)) {
            float g2 = fmaxf(v, 0.f);
            Cb[(size_t)(gmb + r) * (W13_N / 2) + (gn >> 1)] = (bf16)(g2 * g2 * pv);
          }
        }
      }
    }
  }
}

// ---------------- GEMM (big, fused fp32-W): 256x256, 8 waves, counted-vmcnt dbuf ----------
// v2 schedule: BWRITE moved to TILE TOP (bregs a full tile old -> wait free);
// prefetch order pinned STAGEA (oldest) then BLOAD; end-of-tile vmcnt(8)
// retires only the 4 STAGEA events, keeps the 8 B-loads in flight.
//   [BWRITE(kt); lgkmcnt(0); barrier;
//    prefetch kt+1 {STAGEA x2, BLOAD};
//    4 quadrant phases (ds_read + lgkmcnt(0) + MFMA);
//    vmcnt(8); barrier]
template<int EPI>
__global__ __launch_bounds__(512, 1) void gemm_2pf(const bf16* __restrict__ A,
                                                   const float* __restrict__ W,
                                                   float* __restrict__ C, bf16* __restrict__ Cb,
                                                   int K, int ldc) {
  extern __shared__ __align__(16) char lds[];
  char* ldsA = lds;            // [2 buf][2 half][128 rows][128 B] = 64 KB
  char* ldsB = lds + 65536;
  const int t = threadIdx.x;
  int mtile, ntile;
  xcd_remap(gridDim.x, gridDim.y, mtile, ntile);
  const int m0 = mtile * 256, n0 = ntile * 256;
  const int wid = t >> 6, lane = t & 63;
  const int lo = lane & 15, hi = lane >> 4;
  const int wr = wid >> 2, wc = wid & 3;

  f32x4 acc[8][4];
#pragma unroll
  for (int f = 0; f < 8; ++f)
#pragma unroll
    for (int g = 0; g < 4; ++g) acc[f][g] = (f32x4){0.f, 0.f, 0.f, 0.f};

  const int prow = t >> 3;
  const int pcol = (t & 7) * 16;

  auto STAGEA = [&](int h, int kt2) {
    char* dst = ldsA + (kt2 & 1) * 32768 + h * 16384;
    const int k0 = kt2 * 64;
#pragma unroll
    for (int i = 0; i < 2; ++i) {
      int row = i * 64 + prow;
      int srcb = pcol ^ ((row & 7) << 4);
      const bf16* g = A + (size_t)(m0 + h * 128 + row) * K + k0 + (srcb >> 1);
      __builtin_amdgcn_global_load_lds((const AS1 void*)g,
          (AS3 void*)(dst + i * 8192 + wid * 1024), 16, 0, 0);
    }
  };

  f32x4 breg[4][2];
  auto BLOAD = [&](int kt2) {
#pragma unroll
    for (int i = 0; i < 4; ++i) {
      int c = t + i * 512;
      int row = c >> 3, kc = c & 7;
      const float* g = W + (size_t)(n0 + row) * K + kt2 * 64 + kc * 8;
      breg[i][0] = *(const f32x4*)(g);
      breg[i][1] = *(const f32x4*)(g + 4);
    }
  };
  auto BWRITE = [&](int kt2) {
#pragma unroll
    for (int i = 0; i < 4; ++i) {
      int c = t + i * 512;
      int row = c >> 3, kc = c & 7;
      int h = row >> 7, rowh = row & 127;
      bf16x8 bv;
#pragma unroll
      for (int e = 0; e < 4; ++e) {
        bv[e]     = (bf16)breg[i][0][e];
        bv[4 + e] = (bf16)breg[i][1][e];
      }
      *(bf16x8*)(ldsB + (kt2 & 1) * 32768 + h * 16384 + rowh * 128 +
                 ((kc * 16) ^ ((rowh & 7) << 4))) = bv;
    }
  };

  auto LDA = [&](int buf, int mh, int i, int ks) -> bf16x8 {
    int row = (mh * 4 + i) * 16 + lo;
    return *(const bf16x8*)(ldsA + buf * 32768 + wr * 16384 + row * 128 +
                            ((ks * 64 + hi * 16) ^ ((row & 7) << 4)));
  };
  auto LDB = [&](int buf, int nh, int j, int ks) -> bf16x8 {
    int rowh = (wc & 1) * 64 + (nh * 2 + j) * 16 + lo;
    return *(const bf16x8*)(ldsB + buf * 32768 + (wc >> 1) * 16384 + rowh * 128 +
                            ((ks * 64 + hi * 16) ^ ((rowh & 7) << 4)));
  };

  const int nk = K / 64;
  // prologue: issue tile-0 prefetch (A stages oldest, then B reg loads)
  STAGEA(0, 0);
  STAGEA(1, 0);
  __builtin_amdgcn_sched_barrier(0);
  BLOAD(0);
  __builtin_amdgcn_sched_barrier(0);
  asm volatile("s_waitcnt vmcnt(8)" ::: "memory");   // A(0) landed; B(0) may fly
  __builtin_amdgcn_s_barrier();

  for (int kt = 0; kt < nk; ++kt) {
    const int buf = kt & 1;
    const bool more = (kt + 1) < nk;
    // write B(kt) from bregs (loaded a full tile ago; reg-dep wait ~free)
    BWRITE(kt);
    asm volatile("s_waitcnt lgkmcnt(0)" ::: "memory");
    __builtin_amdgcn_s_barrier();
    // prefetch kt+1 (A stages first = oldest in vm queue)
    if (more) {
      STAGEA(0, kt + 1);
      STAGEA(1, kt + 1);
      __builtin_amdgcn_sched_barrier(0);
      BLOAD(kt + 1);
      __builtin_amdgcn_sched_barrier(0);
    }
    // compute 4 quadrants from buf
#pragma unroll
    for (int mh = 0; mh < 2; ++mh) {
      bf16x8 a[4][2];
#pragma unroll
      for (int i = 0; i < 4; ++i) { a[i][0] = LDA(buf, mh, i, 0); a[i][1] = LDA(buf, mh, i, 1); }
#pragma unroll
      for (int nh = 0; nh < 2; ++nh) {
        bf16x8 b[2][2];
#pragma unroll
        for (int j = 0; j < 2; ++j) { b[j][0] = LDB(buf, nh, j, 0); b[j][1] = LDB(buf, nh, j, 1); }
        asm volatile("s_waitcnt lgkmcnt(0)" ::: "memory");
        __builtin_amdgcn_sched_barrier(0);
        __builtin_amdgcn_s_setprio(1);
#pragma unroll
        for (int i = 0; i < 4; ++i)
#pragma unroll
          for (int j = 0; j < 2; ++j) {
            acc[mh * 4 + i][nh * 2 + j] = mfma16(a[i][0], b[j][0], acc[mh * 4 + i][nh * 2 + j]);
            acc[mh * 4 + i][nh * 2 + j] = mfma16(a[i][1], b[j][1], acc[mh * 4 + i][nh * 2 + j]);
          }
        __builtin_amdgcn_s_setprio(0);
      }
    }
    // retire only the A stages (oldest 4 events); keep B loads in flight
    if (more) asm volatile("s_waitcnt vmcnt(8)" ::: "memory");
    else      asm volatile("s_waitcnt vmcnt(0)" ::: "memory");
    __builtin_amdgcn_s_barrier();
  }
  // epilogue
#pragma unroll
  for (int f = 0; f < 8; ++f) {
    int gmb = m0 + wr * 128 + f * 16 + hi * 4;
#pragma unroll
    for (int g = 0; g < 4; ++g) {
      int gn = n0 + wc * 64 + g * 16 + lo;
#pragma unroll
      for (int r = 0; r < 4; ++r) {
        float v = acc[f][g][r];
        if (EPI == EPI_STORE) {
          C[(size_t)(gmb + r) * ldc + gn] = v;
        } else if (EPI == EPI_ADD) {
          C[(size_t)(gmb + r) * ldc + gn] += v;
        } else {
          float pv = __shfl_xor(v, 1);
          if (!(lane & 1)) {
            float g2 = fmaxf(v, 0.f);
            Cb[(size_t)(gmb + r) * (W13_N / 2) + (gn >> 1)] = (bf16)(g2 * g2 * pv);
          }
        }
      }
    }
  }
}

// ---------------- launch ----------------
extern "C" void kernel_launch(void* const* d_in, const int* in_sizes, int n_in,
                              void* d_out, int out_size, void* d_ws, size_t ws_size,
                              hipStream_t stream) {
  const int* tokens = (const int*)d_in[0];
  const float* img_feats = (const float*)d_in[1];
  const float* freqs = (const float*)d_in[2];
  const float* freqs2 = (const float*)d_in[3];
  const float* tok_emb = (const float*)d_in[4];
  const float* img_proj_w = (const float*)d_in[5];
  const float* wqkv = (const float*)d_in[6];
  const float* wo = (const float*)d_in[7];
  const float* sinks = (const float*)d_in[8];
  const float* w13 = (const float*)d_in[9];
  const float* w2 = (const float*)d_in[10];
  const float* norm_w = (const float*)d_in[11];
  const float* output_w = (const float*)d_in[12];
  float* out = (float*)d_out;

  char* ws = (char*)d_ws;
  float* x = (float*)ws;   ws += (size_t)S_LEN * DIM * 4;
  bf16* h = (bf16*)ws;     ws += (size_t)S_LEN * DIM * 2;
  float* qkv = (float*)ws; ws += (size_t)S_LEN * QKV_N * 4;
  bf16* qb = (bf16*)ws;    ws += (size_t)NH * S_LEN * HD * 2;
  bf16* kb = (bf16*)ws;    ws += (size_t)NKVH * S_LEN * HD * 2;
  bf16* vtb = (bf16*)ws;   ws += (size_t)NKVH * HD * S_LEN * 2;
  bf16* ao = (bf16*)ws;    ws += (size_t)S_LEN * DIM * 2;
  bf16* act = (bf16*)ws;   ws += (size_t)S_LEN * HID * 2;
  bf16* imgb = (bf16*)ws;  ws += (size_t)NIMG * IMG_K * 2;
  const size_t n_wqkv = (size_t)2 * QKV_N * DIM;
  const size_t n_wo   = (size_t)2 * DIM * (NH * HD);
  const size_t n_w2   = (size_t)2 * DIM * HID;
  bf16* wqkvb = (bf16*)ws; ws += n_wqkv * 2;
  bf16* wob   = (bf16*)ws; ws += n_wo * 2;
  bf16* w2b   = (bf16*)ws; ws += n_w2 * 2;
  const bool bf16_path = ((size_t)(ws - (char*)d_ws) <= ws_size);

  bool big_ok = false;
  {
    hipError_t e1 = hipFuncSetAttribute((const void*)&gemm_2pf<EPI_STORE>,
                                        hipFuncAttributeMaxDynamicSharedMemorySize, 131072);
    hipError_t e2 = hipFuncSetAttribute((const void*)&gemm_2pf<EPI_ACT>,
                                        hipFuncAttributeMaxDynamicSharedMemorySize, 131072);
    if (e1 == hipSuccess && e2 == hipSuccess) {
      hipFuncAttributes fa1{}, fa2{};
      if (hipFuncGetAttributes(&fa1, (const void*)&gemm_2pf<EPI_STORE>) == hipSuccess &&
          hipFuncGetAttributes(&fa2, (const void*)&gemm_2pf<EPI_ACT>) == hipSuccess)
        big_ok = fa1.maxDynamicSharedSizeBytes >= 131072 &&
                 fa2.maxDynamicSharedSizeBytes >= 131072;
    }
  }

  embed_kernel<<<S_LEN, 256, 0, stream>>>(tokens, tok_emb, x);
  cvt_kernel<<<(NIMG * IMG_K + 255) / 256, 256, 0, stream>>>(img_feats, imgb, NIMG * IMG_K);
  gemm_bt<64, 128, EPI_STORE, 0><<<dim3(NIMG / 64, DIM / 128), 256, 0, stream>>>(
      imgb, img_proj_w, x + DIM, nullptr, NIMG, DIM, IMG_K, DIM);

  if (bf16_path) {
    cvt4_kernel<<<(int)(n_wqkv / 4 + 255) / 256, 256, 0, stream>>>(wqkv, wqkvb, (int)(n_wqkv / 4));
    cvt4_kernel<<<(int)(n_wo / 4 + 255) / 256, 256, 0, stream>>>(wo, wob, (int)(n_wo / 4));
    cvt4_kernel<<<(int)(n_w2 / 4 + 255) / 256, 256, 0, stream>>>(w2, w2b, (int)(n_w2 / 4));
  }

  for (int i = 0; i < 2; ++i) {
    rmsnorm_kernel<0><<<S_LEN, 256, 0, stream>>>(x, nullptr, h);
    if (bf16_path) {
      gemm_bb<64, 128, EPI_STORE><<<dim3(S_LEN / 64, QKV_N / 128), 256, 0, stream>>>(
          h, wqkvb + (size_t)i * QKV_N * DIM, qkv, nullptr, DIM, QKV_N);
    } else {
      gemm_bt<64, 128, EPI_STORE, 1><<<dim3(S_LEN / 64, QKV_N / 128), 256, 0, stream>>>(
          h, wqkv + (size_t)i * QKV_N * DIM, qkv, nullptr, S_LEN, QKV_N, DIM, QKV_N);
    }
    qkvpost_kernel<<<S_LEN, 256, 0, stream>>>(qkv, freqs, freqs2, qb, kb, vtb);
    attn_kernel<<<dim3(S_LEN / 16, NH), 256, 0, stream>>>(qb, kb, vtb, sinks + i * NH, ao);
    if (bf16_path) {
      gemm_bb<64, 128, EPI_ADD><<<dim3(S_LEN / 64, DIM / 128), 256, 0, stream>>>(
          ao, wob + (size_t)i * DIM * DIM, x, nullptr, DIM, DIM);
    } else {
      gemm_bt<64, 128, EPI_ADD, 1><<<dim3(S_LEN / 64, DIM / 128), 256, 0, stream>>>(
          ao, wo + (size_t)i * DIM * DIM, x, nullptr, S_LEN, DIM, DIM, DIM);
    }
    rmsnorm_kernel<0><<<S_LEN, 256, 0, stream>>>(x, nullptr, h);
    if (big_ok) {
      gemm_2pf<EPI_ACT><<<dim3(S_LEN / 256, W13_N / 256), 512, 131072, stream>>>(
          h, w13 + (size_t)i * W13_N * DIM, nullptr, act, DIM, 0);
    } else {
      gemm_bt<128, 128, EPI_ACT, 1><<<dim3(S_LEN / 128, W13_N / 128), 256, 0, stream>>>(
          h, w13 + (size_t)i * W13_N * DIM, nullptr, act, S_LEN, W13_N, DIM, 0);
    }
    if (bf16_path) {
      gemm_bb<64, 128, EPI_ADD><<<dim3(S_LEN / 64, DIM / 128), 256, 0, stream>>>(
          act, w2b + (size_t)i * DIM * HID, x, nullptr, HID, DIM);
    } else {
      gemm_bt<64, 128, EPI_ADD, 1><<<dim3(S_LEN / 64, DIM / 128), 256, 0, stream>>>(
          act, w2 + (size_t)i * DIM * HID, x, nullptr, S_LEN, DIM, HID, DIM);
    }
  }
  rmsnorm_kernel<1><<<S_LEN, 256, 0, stream>>>(x, norm_w, h);
  if (big_ok) {
    gemm_2pf<EPI_STORE><<<dim3(S_LEN / 256, VOCAB / 256), 512, 131072, stream>>>(
        h, output_w, out, nullptr, DIM, VOCAB);
  } else {
    gemm_bt<128, 128, EPI_STORE, 1><<<dim3(S_LEN / 128, VOCAB / 128), 256, 0, stream>>>(
        h, output_w, out, nullptr, S_LEN, VOCAB, DIM, VOCAB);
  }
}

// Round 14
// 1030.637 us; speedup vs baseline: 1.0344x; 1.0021x over previous
//
#include <hip/hip_runtime.h>

typedef __bf16 bf16;
typedef bf16 bf16x8 __attribute__((ext_vector_type(8)));
typedef bf16 bf16x4 __attribute__((ext_vector_type(4)));
typedef bf16 bf16x2 __attribute__((ext_vector_type(2)));
typedef float f32x4 __attribute__((ext_vector_type(4)));
typedef float f32x2 __attribute__((ext_vector_type(2)));

#define S_LEN 1024
#define DIM 2048
#define NH 16
#define NKVH 4
#define HD 128
#define HID 8192
#define VOCAB 32000
#define QKV_N 3072
#define W13_N 16384
#define IMG_K 1176
#define NIMG 256

#define AS1 __attribute__((address_space(1)))
#define AS3 __attribute__((address_space(3)))

__device__ inline f32x4 mfma16(bf16x8 a, bf16x8 b, f32x4 c) {
  return __builtin_amdgcn_mfma_f32_16x16x32_bf16(a, b, c, 0, 0, 0);
}

// ---------------- embed ----------------
__global__ void embed_kernel(const int* __restrict__ tok, const float* __restrict__ emb,
                             float* __restrict__ x) {
  int s = blockIdx.x, t = threadIdx.x;
  int id = tok[s];
  const float* er = emb + (size_t)id * DIM;
  float* xr = x + (size_t)s * DIM;
  *(f32x4*)(xr + t * 8)     = *(const f32x4*)(er + t * 8);
  *(f32x4*)(xr + t * 8 + 4) = *(const f32x4*)(er + t * 8 + 4);
}

// ---------------- fp32 -> bf16 converts ----------------
__global__ void cvt_kernel(const float* __restrict__ in, bf16* __restrict__ o, int n) {
  int i = blockIdx.x * 256 + threadIdx.x;
  if (i < n) o[i] = (bf16)in[i];
}
__global__ void cvt4_kernel(const float* __restrict__ in, bf16* __restrict__ o, int n4) {
  int i = blockIdx.x * 256 + threadIdx.x;
  if (i < n4) {
    f32x4 v = *(const f32x4*)(in + (size_t)i * 4);
    bf16x4 b;
    b[0] = (bf16)v[0]; b[1] = (bf16)v[1]; b[2] = (bf16)v[2]; b[3] = (bf16)v[3];
    *(bf16x4*)(o + (size_t)i * 4) = b;
  }
}

// ---------------- rmsnorm (x fp32 -> bf16) ----------------
template<int USE_W>
__global__ void rmsnorm_kernel(const float* __restrict__ x, const float* __restrict__ w,
                               bf16* __restrict__ o) {
  const int row = blockIdx.x, t = threadIdx.x;
  const float* xr = x + (size_t)row * DIM;
  f32x4 a = *(const f32x4*)(xr + t * 8);
  f32x4 b = *(const f32x4*)(xr + t * 8 + 4);
  float ss = a[0]*a[0] + a[1]*a[1] + a[2]*a[2] + a[3]*a[3]
           + b[0]*b[0] + b[1]*b[1] + b[2]*b[2] + b[3]*b[3];
#pragma unroll
  for (int off = 1; off < 64; off <<= 1) ss += __shfl_xor(ss, off);
  __shared__ float red[4];
  if ((t & 63) == 0) red[t >> 6] = ss;
  __syncthreads();
  ss = red[0] + red[1] + red[2] + red[3];
  float r = rsqrtf(ss * (1.0f / DIM) + 1e-6f);
  bf16x8 ov;
  if (USE_W) {
    f32x4 w1 = *(const f32x4*)(w + t * 8);
    f32x4 w2v = *(const f32x4*)(w + t * 8 + 4);
    ov[0] = (bf16)(a[0]*r*w1[0]); ov[1] = (bf16)(a[1]*r*w1[1]);
    ov[2] = (bf16)(a[2]*r*w1[2]); ov[3] = (bf16)(a[3]*r*w1[3]);
    ov[4] = (bf16)(b[0]*r*w2v[0]); ov[5] = (bf16)(b[1]*r*w2v[1]);
    ov[6] = (bf16)(b[2]*r*w2v[2]); ov[7] = (bf16)(b[3]*r*w2v[3]);
  } else {
    ov[0] = (bf16)(a[0]*r); ov[1] = (bf16)(a[1]*r);
    ov[2] = (bf16)(a[2]*r); ov[3] = (bf16)(a[3]*r);
    ov[4] = (bf16)(b[0]*r); ov[5] = (bf16)(b[1]*r);
    ov[6] = (bf16)(b[2]*r); ov[7] = (bf16)(b[3]*r);
  }
  *(bf16x8*)(o + (size_t)row * DIM + t * 8) = ov;
}

// ---------------- qkv post: per-head rms + rope, write q/k/vT bf16 ----------------
__global__ void qkvpost_kernel(const float* __restrict__ qkv, const float* __restrict__ f1,
                               const float* __restrict__ f2, bf16* __restrict__ qb,
                               bf16* __restrict__ kb, bf16* __restrict__ vtb) {
  int s = blockIdx.x, t = threadIdx.x;
  __shared__ float cs[64], sn[64];
  if (t < 64) {
    float ang = (t < 32) ? f1[(size_t)s * 32 + t] : f2[(size_t)s * 32 + (t - 32)];
    cs[t] = cosf(ang);
    sn[t] = sinf(ang);
  }
  __syncthreads();
  int w = t >> 6, lane = t & 63;
  for (int hh = w; hh < 24; hh += 4) {
    const float* base = qkv + (size_t)s * QKV_N + hh * HD;
    f32x2 e = *(const f32x2*)(base + lane * 2);
    if (hh < 20) {
      float ssum = e[0]*e[0] + e[1]*e[1];
#pragma unroll
      for (int off = 1; off < 64; off <<= 1) ssum += __shfl_xor(ssum, off);
      float r = rsqrtf(ssum * (1.0f / HD) + 1e-6f);
      float x1 = e[0] * r, x2 = e[1] * r;
      float c = cs[lane], s2 = sn[lane];
      bf16x2 ov;
      ov[0] = (bf16)(x1 * c - x2 * s2);
      ov[1] = (bf16)(x1 * s2 + x2 * c);
      if (hh < 16)
        *(bf16x2*)(qb + ((size_t)hh * S_LEN + s) * HD + lane * 2) = ov;
      else
        *(bf16x2*)(kb + ((size_t)(hh - 16) * S_LEN + s) * HD + lane * 2) = ov;
    } else {
      int kv = hh - 20;
      vtb[((size_t)kv * HD + lane * 2) * S_LEN + s]     = (bf16)e[0];
      vtb[((size_t)kv * HD + lane * 2 + 1) * S_LEN + s] = (bf16)e[1];
    }
  }
}

// ---------------- flash attention, KV-split across 4 waves ----------------
__global__ __launch_bounds__(256) void attn_kernel(const bf16* __restrict__ qb,
                                                   const bf16* __restrict__ kb,
                                                   const bf16* __restrict__ vtb,
                                                   const float* __restrict__ sinks,
                                                   bf16* __restrict__ out) {
  const int h = blockIdx.y, qs = blockIdx.x;
  const int w = threadIdx.x >> 6, lane = threadIdx.x & 63;
  const int lo = lane & 15, hi = lane >> 4;
  const int q0 = qs * 16;
  const int q = q0 + lo;
  const int kvh = h >> 2;
  const bf16* Q = qb + (size_t)h * S_LEN * HD;
  const bf16* Kp = kb + (size_t)kvh * S_LEN * HD;
  const bf16* Vt = vtb + (size_t)kvh * HD * S_LEN;
  const float scale = 0.08838834764831845f;

  __shared__ float accS[4][64 * 36];
  __shared__ float mS[4][16], lS[4][16];

  bf16x8 qf[4];
#pragma unroll
  for (int ks = 0; ks < 4; ++ks)
    qf[ks] = *(const bf16x8*)(Q + (size_t)q * HD + ks * 32 + hi * 8);

  f32x4 accT[8];
#pragma unroll
  for (int i = 0; i < 8; ++i) accT[i] = (f32x4){0.f, 0.f, 0.f, 0.f};
  float mrow = -3e38f, lrow = 0.f;

  const int nt = (q0 + 15) / 32 + 1;
  for (int tile = w; tile < nt; tile += 4) {
    const int kv0 = tile * 32;
    f32x4 st0 = (f32x4){0.f,0.f,0.f,0.f}, st1 = (f32x4){0.f,0.f,0.f,0.f};
#pragma unroll
    for (int ks = 0; ks < 4; ++ks) {
      const bf16* kbase = Kp + (size_t)(kv0 + lo) * HD + ks * 32 + hi * 8;
      bf16x8 k0f = *(const bf16x8*)(kbase);
      bf16x8 k1f = *(const bf16x8*)(kbase + 16 * HD);
      st0 = mfma16(k0f, qf[ks], st0);
      st1 = mfma16(k1f, qf[ks], st1);
    }
    float p[2][4];
    float pmax = -3e38f;
#pragma unroll
    for (int r = 0; r < 4; ++r) {
      int kvg0 = kv0 + hi * 4 + r;
      float v0 = (kvg0 <= q) ? st0[r] * scale : -3e38f;
      int kvg1 = kvg0 + 16;
      float v1 = (kvg1 <= q) ? st1[r] * scale : -3e38f;
      p[0][r] = v0; p[1][r] = v1;
      pmax = fmaxf(pmax, fmaxf(v0, v1));
    }
    pmax = fmaxf(pmax, __shfl_xor(pmax, 16));
    pmax = fmaxf(pmax, __shfl_xor(pmax, 32));
    float mnew = fmaxf(mrow, pmax);
    float alpha = __expf(mrow - mnew);
    float ps = 0.f;
#pragma unroll
    for (int f = 0; f < 2; ++f)
#pragma unroll
      for (int r = 0; r < 4; ++r) {
        float e = __expf(p[f][r] - mnew);
        p[f][r] = e;
        ps += e;
      }
    ps += __shfl_xor(ps, 16);
    ps += __shfl_xor(ps, 32);
    lrow = lrow * alpha + ps;
    mrow = mnew;
#pragma unroll
    for (int fd = 0; fd < 8; ++fd) {
      accT[fd][0] *= alpha; accT[fd][1] *= alpha;
      accT[fd][2] *= alpha; accT[fd][3] *= alpha;
    }
    bf16x8 pb;
#pragma unroll
    for (int j = 0; j < 8; ++j) {
      int src = ((j >> 2) + 2 * (hi & 1)) * 16 + lo;
      float v0 = __shfl(p[0][j & 3], src);
      float v1 = __shfl(p[1][j & 3], src);
      pb[j] = (bf16)((hi >= 2) ? v1 : v0);
    }
#pragma unroll
    for (int fd = 0; fd < 8; ++fd) {
      bf16x8 vf = *(const bf16x8*)(Vt + (size_t)(fd * 16 + lo) * S_LEN + kv0 + hi * 8);
      accT[fd] = mfma16(vf, pb, accT[fd]);
    }
  }
  if (hi == 0) { mS[w][lo] = mrow; lS[w][lo] = lrow; }
  float* as = &accS[w][lane * 36];
#pragma unroll
  for (int fd = 0; fd < 8; ++fd) *(f32x4*)(as + fd * 4) = accT[fd];
  __syncthreads();
  float m0 = mS[0][lo], m1 = mS[1][lo], m2 = mS[2][lo], m3 = mS[3][lo];
  float mstar = fmaxf(fmaxf(m0, m1), fmaxf(m2, m3));
  float e0 = __expf(m0 - mstar), e1 = __expf(m1 - mstar);
  float e2 = __expf(m2 - mstar), e3 = __expf(m3 - mstar);
  float lstar = lS[0][lo]*e0 + lS[1][lo]*e1 + lS[2][lo]*e2 + lS[3][lo]*e3;
  float lse = mstar + __logf(lstar);
  float ssig = 1.f / (1.f + __expf(sinks[h] - lse));
  float sc = ssig / lstar;
#pragma unroll
  for (int f2 = 0; f2 < 2; ++f2) {
    int fd = w * 2 + f2;
    f32x4 a0 = *(const f32x4*)&accS[0][lane * 36 + fd * 4];
    f32x4 a1 = *(const f32x4*)&accS[1][lane * 36 + fd * 4];
    f32x4 a2 = *(const f32x4*)&accS[2][lane * 36 + fd * 4];
    f32x4 a3 = *(const f32x4*)&accS[3][lane * 36 + fd * 4];
#pragma unroll
    for (int r = 0; r < 4; ++r) {
      float o = a0[r]*e0 + a1[r]*e1 + a2[r]*e2 + a3[r]*e3;
      out[(size_t)q * DIM + h * HD + fd * 16 + hi * 4 + r] = (bf16)(o * sc);
    }
  }
}

// ---------------- XCD-aware (m,n) remap helper ----------------
__device__ inline void xcd_remap(int ntm, int ntn, int& mtile, int& ntile) {
  const int flat = blockIdx.x + ntm * blockIdx.y;
  const int chunk = ntm * 8;
  const int gfull = ntn >> 3;
  const int g = flat / chunk;
  if (g < gfull) {
    int rem = flat - g * chunk;
    ntile = g * 8 + (rem & 7);
    mtile = rem >> 3;
  } else {
    int rem = flat - gfull * chunk;
    int nrem = ntn - gfull * 8;
    ntile = gfull * 8 + rem % nrem;
    mtile = rem / nrem;
  }
}

enum { EPI_STORE = 0, EPI_ADD = 1, EPI_ACT = 2 };

// ---------------- GEMM (fp32-W / img / small): W fp32, reg-staged ----------------
template<int BM, int BN, int EPI, int GL>
__global__ void gemm_bt(const bf16* __restrict__ A, const float* __restrict__ W,
                        float* __restrict__ C, bf16* __restrict__ Cb,
                        int M, int N, int K, int ldc) {
  constexpr int BK = 64;
  __shared__ __align__(16) char lds[(BM + BN) * BK * 2];
  char* ldsA = lds;
  char* ldsB = lds + BM * BK * 2;
  const int t = threadIdx.x;
  int mtile, ntile;
  xcd_remap(gridDim.x, gridDim.y, mtile, ntile);
  const int m0 = mtile * BM, n0 = ntile * BN;

  const int wid = t >> 6, lane = t & 63;
  const int lo = lane & 15, hi = lane >> 4;
  const int wr = wid >> 1, wc = wid & 1;
  constexpr int TM = BM / 32, TN = BN / 32;
  constexpr int NA = BM / 32;
  constexpr int NPASS = BM / 32;
  constexpr int NW = BN / 16;

  f32x4 acc[TM][TN];
#pragma unroll
  for (int m = 0; m < TM; ++m)
#pragma unroll
    for (int n = 0; n < TN; ++n) acc[m][n] = (f32x4){0.f, 0.f, 0.f, 0.f};

  const int nk = (K + BK - 1) / BK;
  for (int kt = 0; kt < nk; ++kt) {
    const int k0 = kt * BK;
    bf16x8 av[NA];
    f32x4 wv[NW];
    if (!GL) {
#pragma unroll
      for (int i = 0; i < NA; ++i) {
        int c = t + i * 256;
        int row = c >> 3, kc = c & 7;
        int kg = k0 + kc * 8;
        bf16x8 z = {};
        av[i] = (kg < K) ? *(const bf16x8*)(A + (size_t)(m0 + row) * K + kg) : z;
      }
    }
#pragma unroll
    for (int i = 0; i < NW; ++i) {
      int c = t + i * 256;
      int row = c >> 4, kc = c & 15;
      int kg = k0 + kc * 4;
      f32x4 z = (f32x4){0.f, 0.f, 0.f, 0.f};
      wv[i] = (kg < K) ? *(const f32x4*)(W + (size_t)(n0 + row) * K + kg) : z;
    }
    __syncthreads();
    if (GL) {
#pragma unroll
      for (int i = 0; i < NPASS; ++i) {
        int row = i * 32 + (t >> 3);
        int srcb = ((t & 7) * 16) ^ ((row & 7) << 4);
        const bf16* g2 = A + (size_t)(m0 + row) * K + k0 + (srcb >> 1);
        char* l = ldsA + i * 4096 + wid * 1024;
        __builtin_amdgcn_global_load_lds((const AS1 void*)g2, (AS3 void*)l, 16, 0, 0);
      }
    } else {
#pragma unroll
      for (int i = 0; i < NA; ++i) {
        int c = t + i * 256;
        int row = c >> 3, kc = c & 7;
        int kb = (kc * 16) ^ ((row & 7) << 4);
        *(bf16x8*)(ldsA + row * 128 + kb) = av[i];
      }
    }
#pragma unroll
    for (int i = 0; i < NW; ++i) {
      int c = t + i * 256;
      int row = c >> 4, kc = c & 15;
      bf16x4 bv;
      bv[0] = (bf16)wv[i][0]; bv[1] = (bf16)wv[i][1];
      bv[2] = (bf16)wv[i][2]; bv[3] = (bf16)wv[i][3];
      int kb = (kc * 8) ^ ((row & 7) << 4);
      *(bf16x4*)(ldsB + row * 128 + kb) = bv;
    }
    __syncthreads();
#pragma unroll
    for (int ks = 0; ks < 2; ++ks) {
      bf16x8 af[TM], bfr[TN];
      int kbb = ks * 64 + hi * 16;
#pragma unroll
      for (int m = 0; m < TM; ++m) {
        int row = wr * (BM / 2) + m * 16 + lo;
        af[m] = *(const bf16x8*)(ldsA + row * 128 + (kbb ^ ((row & 7) << 4)));
      }
#pragma unroll
      for (int n = 0; n < TN; ++n) {
        int row = wc * (BN / 2) + n * 16 + lo;
        bfr[n] = *(const bf16x8*)(ldsB + row * 128 + (kbb ^ ((row & 7) << 4)));
      }
#pragma unroll
      for (int m = 0; m < TM; ++m)
#pragma unroll
        for (int n = 0; n < TN; ++n)
          acc[m][n] = mfma16(af[m], bfr[n], acc[m][n]);
    }
    __syncthreads();
  }
#pragma unroll
  for (int m = 0; m < TM; ++m) {
    int gmb = m0 + wr * (BM / 2) + m * 16 + hi * 4;
#pragma unroll
    for (int n = 0; n < TN; ++n) {
      int gn = n0 + wc * (BN / 2) + n * 16 + lo;
#pragma unroll
      for (int r = 0; r < 4; ++r) {
        float v = acc[m][n][r];
        if (EPI == EPI_STORE) {
          C[(size_t)(gmb + r) * ldc + gn] = v;
        } else if (EPI == EPI_ADD) {
          C[(size_t)(gmb + r) * ldc + gn] += v;
        } else {
          float pv = __shfl_xor(v, 1);
          if (!(lane & 1)) {
            float g2 = fmaxf(v, 0.f);
            Cb[(size_t)(gmb + r) * (W13_N / 2) + (gn >> 1)] = (bf16)(g2 * g2 * pv);
          }
        }
      }
    }
  }
}

// ---------------- GEMM (mid): both A and W bf16, global_load_lds staged ----------------
template<int BM, int BN, int EPI>
__global__ __launch_bounds__(256) void gemm_bb(const bf16* __restrict__ A,
                                               const bf16* __restrict__ W,
                                               float* __restrict__ C, bf16* __restrict__ Cb,
                                               int K, int ldc) {
  constexpr int BK = 64;
  __shared__ __align__(16) char lds[(BM + BN) * BK * 2];
  char* ldsA = lds;
  char* ldsB = lds + BM * BK * 2;
  const int t = threadIdx.x;
  int mtile, ntile;
  xcd_remap(gridDim.x, gridDim.y, mtile, ntile);
  const int m0 = mtile * BM, n0 = ntile * BN;

  const int wid = t >> 6, lane = t & 63;
  const int lo = lane & 15, hi = lane >> 4;
  const int wr = wid >> 1, wc = wid & 1;
  constexpr int TM = BM / 32, TN = BN / 32;
  constexpr int PA = BM / 32, PB = BN / 32;

  f32x4 acc[TM][TN];
#pragma unroll
  for (int m = 0; m < TM; ++m)
#pragma unroll
    for (int n = 0; n < TN; ++n) acc[m][n] = (f32x4){0.f, 0.f, 0.f, 0.f};

  const int prow = t >> 3;
  const int psrcb = (t & 7) * 16;
  const int nk = K / BK;
  for (int kt = 0; kt < nk; ++kt) {
    const int k0 = kt * BK;
#pragma unroll
    for (int i = 0; i < PA; ++i) {
      int row = i * 32 + prow;
      int srcb = psrcb ^ ((row & 7) << 4);
      const bf16* g = A + (size_t)(m0 + row) * K + k0 + (srcb >> 1);
      __builtin_amdgcn_global_load_lds((const AS1 void*)g,
                                       (AS3 void*)(ldsA + i * 4096 + wid * 1024), 16, 0, 0);
    }
#pragma unroll
    for (int i = 0; i < PB; ++i) {
      int row = i * 32 + prow;
      int srcb = psrcb ^ ((row & 7) << 4);
      const bf16* g = W + (size_t)(n0 + row) * K + k0 + (srcb >> 1);
      __builtin_amdgcn_global_load_lds((const AS1 void*)g,
                                       (AS3 void*)(ldsB + i * 4096 + wid * 1024), 16, 0, 0);
    }
    __syncthreads();
#pragma unroll
    for (int ks = 0; ks < 2; ++ks) {
      bf16x8 af[TM], bfr[TN];
      int kbb = ks * 64 + hi * 16;
#pragma unroll
      for (int m = 0; m < TM; ++m) {
        int row = wr * (BM / 2) + m * 16 + lo;
        af[m] = *(const bf16x8*)(ldsA + row * 128 + (kbb ^ ((row & 7) << 4)));
      }
#pragma unroll
      for (int n = 0; n < TN; ++n) {
        int row = wc * (BN / 2) + n * 16 + lo;
        bfr[n] = *(const bf16x8*)(ldsB + row * 128 + (kbb ^ ((row & 7) << 4)));
      }
#pragma unroll
      for (int m = 0; m < TM; ++m)
#pragma unroll
        for (int n = 0; n < TN; ++n)
          acc[m][n] = mfma16(af[m], bfr[n], acc[m][n]);
    }
    __syncthreads();
  }
#pragma unroll
  for (int m = 0; m < TM; ++m) {
    int gmb = m0 + wr * (BM / 2) + m * 16 + hi * 4;
#pragma unroll
    for (int n = 0; n < TN; ++n) {
      int gn = n0 + wc * (BN / 2) + n * 16 + lo;
#pragma unroll
      for (int r = 0; r < 4; ++r) {
        float v = acc[m][n][r];
        if (EPI == EPI_STORE) {
          C[(size_t)(gmb + r) * ldc + gn] = v;
        } else if (EPI == EPI_ADD) {
          C[(size_t)(gmb + r) * ldc + gn] += v;
        } else {
          float pv = __shfl_xor(v, 1);
          if (!(lane & 1)) {
            float g2 = fmaxf(v, 0.f);
            Cb[(size_t)(gmb + r) * (W13_N / 2) + (gn >> 1)] = (bf16)(g2 * g2 * pv);
          }
        }
      }
    }
  }
}

// ---------------- GEMM (big, fused fp32-W): 256x256, 8 waves, counted-vmcnt dbuf ----------
// v3: removed per-quadrant lgkmcnt(0)+sched_barrier(0) — LDS reads are
// compiler-visible; hipcc emits fine-grained lgkmcnt(N) between ds_read and
// MFMA (m97). Barriers keep a zero-cost compiler fence (asm "" memory) so LDS
// reads can't be hoisted above the BWRITE barrier. Counted vmcnt(8) as in v2.
template<int EPI>
__global__ __launch_bounds__(512, 1) void gemm_2pf(const bf16* __restrict__ A,
                                                   const float* __restrict__ W,
                                                   float* __restrict__ C, bf16* __restrict__ Cb,
                                                   int K, int ldc) {
  extern __shared__ __align__(16) char lds[];
  char* ldsA = lds;            // [2 buf][2 half][128 rows][128 B] = 64 KB
  char* ldsB = lds + 65536;
  const int t = threadIdx.x;
  int mtile, ntile;
  xcd_remap(gridDim.x, gridDim.y, mtile, ntile);
  const int m0 = mtile * 256, n0 = ntile * 256;
  const int wid = t >> 6, lane = t & 63;
  const int lo = lane & 15, hi = lane >> 4;
  const int wr = wid >> 2, wc = wid & 3;

  f32x4 acc[8][4];
#pragma unroll
  for (int f = 0; f < 8; ++f)
#pragma unroll
    for (int g = 0; g < 4; ++g) acc[f][g] = (f32x4){0.f, 0.f, 0.f, 0.f};

  const int prow = t >> 3;
  const int pcol = (t & 7) * 16;

  auto STAGEA = [&](int h, int kt2) {
    char* dst = ldsA + (kt2 & 1) * 32768 + h * 16384;
    const int k0 = kt2 * 64;
#pragma unroll
    for (int i = 0; i < 2; ++i) {
      int row = i * 64 + prow;
      int srcb = pcol ^ ((row & 7) << 4);
      const bf16* g = A + (size_t)(m0 + h * 128 + row) * K + k0 + (srcb >> 1);
      __builtin_amdgcn_global_load_lds((const AS1 void*)g,
          (AS3 void*)(dst + i * 8192 + wid * 1024), 16, 0, 0);
    }
  };

  f32x4 breg[4][2];
  auto BLOAD = [&](int kt2) {
#pragma unroll
    for (int i = 0; i < 4; ++i) {
      int c = t + i * 512;
      int row = c >> 3, kc = c & 7;
      const float* g = W + (size_t)(n0 + row) * K + kt2 * 64 + kc * 8;
      breg[i][0] = *(const f32x4*)(g);
      breg[i][1] = *(const f32x4*)(g + 4);
    }
  };
  auto BWRITE = [&](int kt2) {
#pragma unroll
    for (int i = 0; i < 4; ++i) {
      int c = t + i * 512;
      int row = c >> 3, kc = c & 7;
      int h = row >> 7, rowh = row & 127;
      bf16x8 bv;
#pragma unroll
      for (int e = 0; e < 4; ++e) {
        bv[e]     = (bf16)breg[i][0][e];
        bv[4 + e] = (bf16)breg[i][1][e];
      }
      *(bf16x8*)(ldsB + (kt2 & 1) * 32768 + h * 16384 + rowh * 128 +
                 ((kc * 16) ^ ((rowh & 7) << 4))) = bv;
    }
  };

  auto LDA = [&](int buf, int mh, int i, int ks) -> bf16x8 {
    int row = (mh * 4 + i) * 16 + lo;
    return *(const bf16x8*)(ldsA + buf * 32768 + wr * 16384 + row * 128 +
                            ((ks * 64 + hi * 16) ^ ((row & 7) << 4)));
  };
  auto LDB = [&](int buf, int nh, int j, int ks) -> bf16x8 {
    int rowh = (wc & 1) * 64 + (nh * 2 + j) * 16 + lo;
    return *(const bf16x8*)(ldsB + buf * 32768 + (wc >> 1) * 16384 + rowh * 128 +
                            ((ks * 64 + hi * 16) ^ ((rowh & 7) << 4)));
  };

  const int nk = K / 64;
  // prologue: issue tile-0 prefetch (A stages oldest, then B reg loads)
  STAGEA(0, 0);
  STAGEA(1, 0);
  __builtin_amdgcn_sched_barrier(0);
  BLOAD(0);
  __builtin_amdgcn_sched_barrier(0);
  asm volatile("s_waitcnt vmcnt(8)" ::: "memory");   // A(0) landed; B(0) may fly
  __builtin_amdgcn_s_barrier();
  asm volatile("" ::: "memory");

  for (int kt = 0; kt < nk; ++kt) {
    const int buf = kt & 1;
    const bool more = (kt + 1) < nk;
    // write B(kt) from bregs (loaded a full tile ago; reg-dep wait ~free)
    BWRITE(kt);
    asm volatile("s_waitcnt lgkmcnt(0)" ::: "memory");
    __builtin_amdgcn_s_barrier();
    asm volatile("" ::: "memory");
    // prefetch kt+1 (A stages first = oldest in vm queue)
    if (more) {
      STAGEA(0, kt + 1);
      STAGEA(1, kt + 1);
      __builtin_amdgcn_sched_barrier(0);
      BLOAD(kt + 1);
      __builtin_amdgcn_sched_barrier(0);
    }
    // compute 4 quadrants from buf; compiler inserts fine-grained lgkmcnt
#pragma unroll
    for (int mh = 0; mh < 2; ++mh) {
      bf16x8 a[4][2];
#pragma unroll
      for (int i = 0; i < 4; ++i) { a[i][0] = LDA(buf, mh, i, 0); a[i][1] = LDA(buf, mh, i, 1); }
#pragma unroll
      for (int nh = 0; nh < 2; ++nh) {
        bf16x8 b[2][2];
#pragma unroll
        for (int j = 0; j < 2; ++j) { b[j][0] = LDB(buf, nh, j, 0); b[j][1] = LDB(buf, nh, j, 1); }
        __builtin_amdgcn_s_setprio(1);
#pragma unroll
        for (int i = 0; i < 4; ++i)
#pragma unroll
          for (int j = 0; j < 2; ++j) {
            acc[mh * 4 + i][nh * 2 + j] = mfma16(a[i][0], b[j][0], acc[mh * 4 + i][nh * 2 + j]);
            acc[mh * 4 + i][nh * 2 + j] = mfma16(a[i][1], b[j][1], acc[mh * 4 + i][nh * 2 + j]);
          }
        __builtin_amdgcn_s_setprio(0);
      }
    }
    // retire only the A stages (oldest 4 events); keep B loads in flight
    if (more) asm volatile("s_waitcnt vmcnt(8)" ::: "memory");
    else      asm volatile("s_waitcnt vmcnt(0)" ::: "memory");
    __builtin_amdgcn_s_barrier();
    asm volatile("" ::: "memory");
  }
  // epilogue
#pragma unroll
  for (int f = 0; f < 8; ++f) {
    int gmb = m0 + wr * 128 + f * 16 + hi * 4;
#pragma unroll
    for (int g = 0; g < 4; ++g) {
      int gn = n0 + wc * 64 + g * 16 + lo;
#pragma unroll
      for (int r = 0; r < 4; ++r) {
        float v = acc[f][g][r];
        if (EPI == EPI_STORE) {
          C[(size_t)(gmb + r) * ldc + gn] = v;
        } else if (EPI == EPI_ADD) {
          C[(size_t)(gmb + r) * ldc + gn] += v;
        } else {
          float pv = __shfl_xor(v, 1);
          if (!(lane & 1)) {
            float g2 = fmaxf(v, 0.f);
            Cb[(size_t)(gmb + r) * (W13_N / 2) + (gn >> 1)] = (bf16)(g2 * g2 * pv);
          }
        }
      }
    }
  }
}

// ---------------- launch ----------------
extern "C" void kernel_launch(void* const* d_in, const int* in_sizes, int n_in,
                              void* d_out, int out_size, void* d_ws, size_t ws_size,
                              hipStream_t stream) {
  const int* tokens = (const int*)d_in[0];
  const float* img_feats = (const float*)d_in[1];
  const float* freqs = (const float*)d_in[2];
  const float* freqs2 = (const float*)d_in[3];
  const float* tok_emb = (const float*)d_in[4];
  const float* img_proj_w = (const float*)d_in[5];
  const float* wqkv = (const float*)d_in[6];
  const float* wo = (const float*)d_in[7];
  const float* sinks = (const float*)d_in[8];
  const float* w13 = (const float*)d_in[9];
  const float* w2 = (const float*)d_in[10];
  const float* norm_w = (const float*)d_in[11];
  const float* output_w = (const float*)d_in[12];
  float* out = (float*)d_out;

  char* ws = (char*)d_ws;
  float* x = (float*)ws;   ws += (size_t)S_LEN * DIM * 4;
  bf16* h = (bf16*)ws;     ws += (size_t)S_LEN * DIM * 2;
  float* qkv = (float*)ws; ws += (size_t)S_LEN * QKV_N * 4;
  bf16* qb = (bf16*)ws;    ws += (size_t)NH * S_LEN * HD * 2;
  bf16* kb = (bf16*)ws;    ws += (size_t)NKVH * S_LEN * HD * 2;
  bf16* vtb = (bf16*)ws;   ws += (size_t)NKVH * HD * S_LEN * 2;
  bf16* ao = (bf16*)ws;    ws += (size_t)S_LEN * DIM * 2;
  bf16* act = (bf16*)ws;   ws += (size_t)S_LEN * HID * 2;
  bf16* imgb = (bf16*)ws;  ws += (size_t)NIMG * IMG_K * 2;
  const size_t n_wqkv = (size_t)2 * QKV_N * DIM;
  const size_t n_wo   = (size_t)2 * DIM * (NH * HD);
  const size_t n_w2   = (size_t)2 * DIM * HID;
  bf16* wqkvb = (bf16*)ws; ws += n_wqkv * 2;
  bf16* wob   = (bf16*)ws; ws += n_wo * 2;
  bf16* w2b   = (bf16*)ws; ws += n_w2 * 2;
  const bool bf16_path = ((size_t)(ws - (char*)d_ws) <= ws_size);

  bool big_ok = false;
  {
    hipError_t e1 = hipFuncSetAttribute((const void*)&gemm_2pf<EPI_STORE>,
                                        hipFuncAttributeMaxDynamicSharedMemorySize, 131072);
    hipError_t e2 = hipFuncSetAttribute((const void*)&gemm_2pf<EPI_ACT>,
                                        hipFuncAttributeMaxDynamicSharedMemorySize, 131072);
    if (e1 == hipSuccess && e2 == hipSuccess) {
      hipFuncAttributes fa1{}, fa2{};
      if (hipFuncGetAttributes(&fa1, (const void*)&gemm_2pf<EPI_STORE>) == hipSuccess &&
          hipFuncGetAttributes(&fa2, (const void*)&gemm_2pf<EPI_ACT>) == hipSuccess)
        big_ok = fa1.maxDynamicSharedSizeBytes >= 131072 &&
                 fa2.maxDynamicSharedSizeBytes >= 131072;
    }
  }

  embed_kernel<<<S_LEN, 256, 0, stream>>>(tokens, tok_emb, x);
  cvt_kernel<<<(NIMG * IMG_K + 255) / 256, 256, 0, stream>>>(img_feats, imgb, NIMG * IMG_K);
  gemm_bt<64, 128, EPI_STORE, 0><<<dim3(NIMG / 64, DIM / 128), 256, 0, stream>>>(
      imgb, img_proj_w, x + DIM, nullptr, NIMG, DIM, IMG_K, DIM);

  if (bf16_path) {
    cvt4_kernel<<<(int)(n_wqkv / 4 + 255) / 256, 256, 0, stream>>>(wqkv, wqkvb, (int)(n_wqkv / 4));
    cvt4_kernel<<<(int)(n_wo / 4 + 255) / 256, 256, 0, stream>>>(wo, wob, (int)(n_wo / 4));
    cvt4_kernel<<<(int)(n_w2 / 4 + 255) / 256, 256, 0, stream>>>(w2, w2b, (int)(n_w2 / 4));
  }

  for (int i = 0; i < 2; ++i) {
    rmsnorm_kernel<0><<<S_LEN, 256, 0, stream>>>(x, nullptr, h);
    if (bf16_path) {
      gemm_bb<64, 128, EPI_STORE><<<dim3(S_LEN / 64, QKV_N / 128), 256, 0, stream>>>(
          h, wqkvb + (size_t)i * QKV_N * DIM, qkv, nullptr, DIM, QKV_N);
    } else {
      gemm_bt<64, 128, EPI_STORE, 1><<<dim3(S_LEN / 64, QKV_N / 128), 256, 0, stream>>>(
          h, wqkv + (size_t)i * QKV_N * DIM, qkv, nullptr, S_LEN, QKV_N, DIM, QKV_N);
    }
    qkvpost_kernel<<<S_LEN, 256, 0, stream>>>(qkv, freqs, freqs2, qb, kb, vtb);
    attn_kernel<<<dim3(S_LEN / 16, NH), 256, 0, stream>>>(qb, kb, vtb, sinks + i * NH, ao);
    if (bf16_path) {
      gemm_bb<64, 128, EPI_ADD><<<dim3(S_LEN / 64, DIM / 128), 256, 0, stream>>>(
          ao, wob + (size_t)i * DIM * DIM, x, nullptr, DIM, DIM);
    } else {
      gemm_bt<64, 128, EPI_ADD, 1><<<dim3(S_LEN / 64, DIM / 128), 256, 0, stream>>>(
          ao, wo + (size_t)i * DIM * DIM, x, nullptr, S_LEN, DIM, DIM, DIM);
    }
    rmsnorm_kernel<0><<<S_LEN, 256, 0, stream>>>(x, nullptr, h);
    if (big_ok) {
      gemm_2pf<EPI_ACT><<<dim3(S_LEN / 256, W13_N / 256), 512, 131072, stream>>>(
          h, w13 + (size_t)i * W13_N * DIM, nullptr, act, DIM, 0);
    } else {
      gemm_bt<128, 128, EPI_ACT, 1><<<dim3(S_LEN / 128, W13_N / 128), 256, 0, stream>>>(
          h, w13 + (size_t)i * W13_N * DIM, nullptr, act, S_LEN, W13_N, DIM, 0);
    }
    if (bf16_path) {
      gemm_bb<64, 128, EPI_ADD><<<dim3(S_LEN / 64, DIM / 128), 256, 0, stream>>>(
          act, w2b + (size_t)i * DIM * HID, x, nullptr, HID, DIM);
    } else {
      gemm_bt<64, 128, EPI_ADD, 1><<<dim3(S_LEN / 64, DIM / 128), 256, 0, stream>>>(
          act, w2 + (size_t)i * DIM * HID, x, nullptr, S_LEN, DIM, HID, DIM);
    }
  }
  rmsnorm_kernel<1><<<S_LEN, 256, 0, stream>>>(x, norm_w, h);
  if (big_ok) {
    gemm_2pf<EPI_STORE><<<dim3(S_LEN / 256, VOCAB / 256), 512, 131072, stream>>>(
        h, output_w, out, nullptr, DIM, VOCAB);
  } else {
    gemm_bt<128, 128, EPI_STORE, 1><<<dim3(S_LEN / 128, VOCAB / 128), 256, 0, stream>>>(
        h, output_w, out, nullptr, S_LEN, VOCAB, DIM, VOCAB);
  }
}

// Round 15
// 894.519 us; speedup vs baseline: 1.1918x; 1.1522x over previous
//
#include <hip/hip_runtime.h>

typedef __bf16 bf16;
typedef bf16 bf16x8 __attribute__((ext_vector_type(8)));
typedef bf16 bf16x4 __attribute__((ext_vector_type(4)));
typedef bf16 bf16x2 __attribute__((ext_vector_type(2)));
typedef float f32x4 __attribute__((ext_vector_type(4)));
typedef float f32x2 __attribute__((ext_vector_type(2)));

#define S_LEN 1024
#define DIM 2048
#define NH 16
#define NKVH 4
#define HD 128
#define HID 8192
#define VOCAB 32000
#define QKV_N 3072
#define W13_N 16384
#define IMG_K 1176
#define NIMG 256

#define AS1 __attribute__((address_space(1)))
#define AS3 __attribute__((address_space(3)))

__device__ inline f32x4 mfma16(bf16x8 a, bf16x8 b, f32x4 c) {
  return __builtin_amdgcn_mfma_f32_16x16x32_bf16(a, b, c, 0, 0, 0);
}

// ---------------- embed ----------------
__global__ void embed_kernel(const int* __restrict__ tok, const float* __restrict__ emb,
                             float* __restrict__ x) {
  int s = blockIdx.x, t = threadIdx.x;
  int id = tok[s];
  const float* er = emb + (size_t)id * DIM;
  float* xr = x + (size_t)s * DIM;
  *(f32x4*)(xr + t * 8)     = *(const f32x4*)(er + t * 8);
  *(f32x4*)(xr + t * 8 + 4) = *(const f32x4*)(er + t * 8 + 4);
}

// ---------------- fp32 -> bf16 converts ----------------
__global__ void cvt_kernel(const float* __restrict__ in, bf16* __restrict__ o, int n) {
  int i = blockIdx.x * 256 + threadIdx.x;
  if (i < n) o[i] = (bf16)in[i];
}
__global__ void cvt4_kernel(const float* __restrict__ in, bf16* __restrict__ o, int n4) {
  int i = blockIdx.x * 256 + threadIdx.x;
  if (i < n4) {
    f32x4 v = *(const f32x4*)(in + (size_t)i * 4);
    bf16x4 b;
    b[0] = (bf16)v[0]; b[1] = (bf16)v[1]; b[2] = (bf16)v[2]; b[3] = (bf16)v[3];
    *(bf16x4*)(o + (size_t)i * 4) = b;
  }
}

// ---------------- rmsnorm (x fp32 -> bf16) ----------------
template<int USE_W>
__global__ void rmsnorm_kernel(const float* __restrict__ x, const float* __restrict__ w,
                               bf16* __restrict__ o) {
  const int row = blockIdx.x, t = threadIdx.x;
  const float* xr = x + (size_t)row * DIM;
  f32x4 a = *(const f32x4*)(xr + t * 8);
  f32x4 b = *(const f32x4*)(xr + t * 8 + 4);
  float ss = a[0]*a[0] + a[1]*a[1] + a[2]*a[2] + a[3]*a[3]
           + b[0]*b[0] + b[1]*b[1] + b[2]*b[2] + b[3]*b[3];
#pragma unroll
  for (int off = 1; off < 64; off <<= 1) ss += __shfl_xor(ss, off);
  __shared__ float red[4];
  if ((t & 63) == 0) red[t >> 6] = ss;
  __syncthreads();
  ss = red[0] + red[1] + red[2] + red[3];
  float r = rsqrtf(ss * (1.0f / DIM) + 1e-6f);
  bf16x8 ov;
  if (USE_W) {
    f32x4 w1 = *(const f32x4*)(w + t * 8);
    f32x4 w2v = *(const f32x4*)(w + t * 8 + 4);
    ov[0] = (bf16)(a[0]*r*w1[0]); ov[1] = (bf16)(a[1]*r*w1[1]);
    ov[2] = (bf16)(a[2]*r*w1[2]); ov[3] = (bf16)(a[3]*r*w1[3]);
    ov[4] = (bf16)(b[0]*r*w2v[0]); ov[5] = (bf16)(b[1]*r*w2v[1]);
    ov[6] = (bf16)(b[2]*r*w2v[2]); ov[7] = (bf16)(b[3]*r*w2v[3]);
  } else {
    ov[0] = (bf16)(a[0]*r); ov[1] = (bf16)(a[1]*r);
    ov[2] = (bf16)(a[2]*r); ov[3] = (bf16)(a[3]*r);
    ov[4] = (bf16)(b[0]*r); ov[5] = (bf16)(b[1]*r);
    ov[6] = (bf16)(b[2]*r); ov[7] = (bf16)(b[3]*r);
  }
  *(bf16x8*)(o + (size_t)row * DIM + t * 8) = ov;
}

// ---------------- qkv post: per-head rms + rope, write q/k/vT bf16 ----------------
__global__ void qkvpost_kernel(const float* __restrict__ qkv, const float* __restrict__ f1,
                               const float* __restrict__ f2, bf16* __restrict__ qb,
                               bf16* __restrict__ kb, bf16* __restrict__ vtb) {
  int s = blockIdx.x, t = threadIdx.x;
  __shared__ float cs[64], sn[64];
  if (t < 64) {
    float ang = (t < 32) ? f1[(size_t)s * 32 + t] : f2[(size_t)s * 32 + (t - 32)];
    cs[t] = cosf(ang);
    sn[t] = sinf(ang);
  }
  __syncthreads();
  int w = t >> 6, lane = t & 63;
  for (int hh = w; hh < 24; hh += 4) {
    const float* base = qkv + (size_t)s * QKV_N + hh * HD;
    f32x2 e = *(const f32x2*)(base + lane * 2);
    if (hh < 20) {
      float ssum = e[0]*e[0] + e[1]*e[1];
#pragma unroll
      for (int off = 1; off < 64; off <<= 1) ssum += __shfl_xor(ssum, off);
      float r = rsqrtf(ssum * (1.0f / HD) + 1e-6f);
      float x1 = e[0] * r, x2 = e[1] * r;
      float c = cs[lane], s2 = sn[lane];
      bf16x2 ov;
      ov[0] = (bf16)(x1 * c - x2 * s2);
      ov[1] = (bf16)(x1 * s2 + x2 * c);
      if (hh < 16)
        *(bf16x2*)(qb + ((size_t)hh * S_LEN + s) * HD + lane * 2) = ov;
      else
        *(bf16x2*)(kb + ((size_t)(hh - 16) * S_LEN + s) * HD + lane * 2) = ov;
    } else {
      int kv = hh - 20;
      vtb[((size_t)kv * HD + lane * 2) * S_LEN + s]     = (bf16)e[0];
      vtb[((size_t)kv * HD + lane * 2 + 1) * S_LEN + s] = (bf16)e[1];
    }
  }
}

// ---------------- flash attention, KV-split across 4 waves, KVBLK=64 ----------------
// One softmax pass + one rescale per 64 kv (was per 32): same MFMA count,
// half the softmax/rescale VALU + shuffles.
__global__ __launch_bounds__(256) void attn_kernel(const bf16* __restrict__ qb,
                                                   const bf16* __restrict__ kb,
                                                   const bf16* __restrict__ vtb,
                                                   const float* __restrict__ sinks,
                                                   bf16* __restrict__ out) {
  const int h = blockIdx.y, qs = blockIdx.x;
  const int w = threadIdx.x >> 6, lane = threadIdx.x & 63;
  const int lo = lane & 15, hi = lane >> 4;
  const int q0 = qs * 16;
  const int q = q0 + lo;
  const int kvh = h >> 2;
  const bf16* Q = qb + (size_t)h * S_LEN * HD;
  const bf16* Kp = kb + (size_t)kvh * S_LEN * HD;
  const bf16* Vt = vtb + (size_t)kvh * HD * S_LEN;
  const float scale = 0.08838834764831845f;

  __shared__ float accS[4][64 * 36];
  __shared__ float mS[4][16], lS[4][16];

  bf16x8 qf[4];
#pragma unroll
  for (int ks = 0; ks < 4; ++ks)
    qf[ks] = *(const bf16x8*)(Q + (size_t)q * HD + ks * 32 + hi * 8);

  f32x4 accT[8];
#pragma unroll
  for (int i = 0; i < 8; ++i) accT[i] = (f32x4){0.f, 0.f, 0.f, 0.f};
  float mrow = -3e38f, lrow = 0.f;

  const int ntc = (q0 + 15) / 64 + 1;   // 64-wide chunks
  for (int c = w; c < ntc; c += 4) {
    const int kv0 = c * 64;
    f32x4 st[4];
#pragma unroll
    for (int f = 0; f < 4; ++f) st[f] = (f32x4){0.f, 0.f, 0.f, 0.f};
#pragma unroll
    for (int ks = 0; ks < 4; ++ks) {
      const bf16* kbase = Kp + (size_t)(kv0 + lo) * HD + ks * 32 + hi * 8;
#pragma unroll
      for (int f = 0; f < 4; ++f) {
        bf16x8 kf = *(const bf16x8*)(kbase + (size_t)f * 16 * HD);
        st[f] = mfma16(kf, qf[ks], st[f]);
      }
    }
    float p[4][4];
    float pmax = -3e38f;
#pragma unroll
    for (int f = 0; f < 4; ++f)
#pragma unroll
      for (int r = 0; r < 4; ++r) {
        int kvg = kv0 + f * 16 + hi * 4 + r;
        float v = (kvg <= q) ? st[f][r] * scale : -3e38f;
        p[f][r] = v;
        pmax = fmaxf(pmax, v);
      }
    pmax = fmaxf(pmax, __shfl_xor(pmax, 16));
    pmax = fmaxf(pmax, __shfl_xor(pmax, 32));
    float mnew = fmaxf(mrow, pmax);
    float alpha = __expf(mrow - mnew);
    float ps = 0.f;
#pragma unroll
    for (int f = 0; f < 4; ++f)
#pragma unroll
      for (int r = 0; r < 4; ++r) {
        float e = __expf(p[f][r] - mnew);
        p[f][r] = e;
        ps += e;
      }
    ps += __shfl_xor(ps, 16);
    ps += __shfl_xor(ps, 32);
    lrow = lrow * alpha + ps;
    mrow = mnew;
#pragma unroll
    for (int fd = 0; fd < 8; ++fd) {
      accT[fd][0] *= alpha; accT[fd][1] *= alpha;
      accT[fd][2] *= alpha; accT[fd][3] *= alpha;
    }
    // rebuild P^T: pb0 covers kv0..kv0+31 (p[0],p[1]); pb1 covers +32..+63 (p[2],p[3])
    bf16x8 pb0, pb1;
#pragma unroll
    for (int j = 0; j < 8; ++j) {
      int src = ((j >> 2) + 2 * (hi & 1)) * 16 + lo;
      float v0 = __shfl(p[0][j & 3], src);
      float v1 = __shfl(p[1][j & 3], src);
      pb0[j] = (bf16)((hi >= 2) ? v1 : v0);
      float v2 = __shfl(p[2][j & 3], src);
      float v3 = __shfl(p[3][j & 3], src);
      pb1[j] = (bf16)((hi >= 2) ? v3 : v2);
    }
#pragma unroll
    for (int fd = 0; fd < 8; ++fd) {
      const bf16* vrow = Vt + (size_t)(fd * 16 + lo) * S_LEN + kv0 + hi * 8;
      bf16x8 vf0 = *(const bf16x8*)(vrow);
      bf16x8 vf1 = *(const bf16x8*)(vrow + 32);
      accT[fd] = mfma16(vf0, pb0, accT[fd]);
      accT[fd] = mfma16(vf1, pb1, accT[fd]);
    }
  }
  if (hi == 0) { mS[w][lo] = mrow; lS[w][lo] = lrow; }
  float* as = &accS[w][lane * 36];
#pragma unroll
  for (int fd = 0; fd < 8; ++fd) *(f32x4*)(as + fd * 4) = accT[fd];
  __syncthreads();
  float m0 = mS[0][lo], m1 = mS[1][lo], m2 = mS[2][lo], m3 = mS[3][lo];
  float mstar = fmaxf(fmaxf(m0, m1), fmaxf(m2, m3));
  float e0 = __expf(m0 - mstar), e1 = __expf(m1 - mstar);
  float e2 = __expf(m2 - mstar), e3 = __expf(m3 - mstar);
  float lstar = lS[0][lo]*e0 + lS[1][lo]*e1 + lS[2][lo]*e2 + lS[3][lo]*e3;
  float lse = mstar + __logf(lstar);
  float ssig = 1.f / (1.f + __expf(sinks[h] - lse));
  float sc = ssig / lstar;
#pragma unroll
  for (int f2 = 0; f2 < 2; ++f2) {
    int fd = w * 2 + f2;
    f32x4 a0 = *(const f32x4*)&accS[0][lane * 36 + fd * 4];
    f32x4 a1 = *(const f32x4*)&accS[1][lane * 36 + fd * 4];
    f32x4 a2 = *(const f32x4*)&accS[2][lane * 36 + fd * 4];
    f32x4 a3 = *(const f32x4*)&accS[3][lane * 36 + fd * 4];
#pragma unroll
    for (int r = 0; r < 4; ++r) {
      float o = a0[r]*e0 + a1[r]*e1 + a2[r]*e2 + a3[r]*e3;
      out[(size_t)q * DIM + h * HD + fd * 16 + hi * 4 + r] = (bf16)(o * sc);
    }
  }
}

// ---------------- XCD-aware (m,n) remap helper ----------------
__device__ inline void xcd_remap(int ntm, int ntn, int& mtile, int& ntile) {
  const int flat = blockIdx.x + ntm * blockIdx.y;
  const int chunk = ntm * 8;
  const int gfull = ntn >> 3;
  const int g = flat / chunk;
  if (g < gfull) {
    int rem = flat - g * chunk;
    ntile = g * 8 + (rem & 7);
    mtile = rem >> 3;
  } else {
    int rem = flat - gfull * chunk;
    int nrem = ntn - gfull * 8;
    ntile = gfull * 8 + rem % nrem;
    mtile = rem / nrem;
  }
}

enum { EPI_STORE = 0, EPI_ADD = 1, EPI_ACT = 2, EPI_ADDA = 3 };

// ---------------- GEMM (fp32-W / img / small): W fp32, reg-staged ----------------
template<int BM, int BN, int EPI, int GL>
__global__ void gemm_bt(const bf16* __restrict__ A, const float* __restrict__ W,
                        float* __restrict__ C, bf16* __restrict__ Cb,
                        int M, int N, int K, int ldc) {
  constexpr int BK = 64;
  __shared__ __align__(16) char lds[(BM + BN) * BK * 2];
  char* ldsA = lds;
  char* ldsB = lds + BM * BK * 2;
  const int t = threadIdx.x;
  int mtile, ntile;
  xcd_remap(gridDim.x, gridDim.y, mtile, ntile);
  const int m0 = mtile * BM, n0 = ntile * BN;

  const int wid = t >> 6, lane = t & 63;
  const int lo = lane & 15, hi = lane >> 4;
  const int wr = wid >> 1, wc = wid & 1;
  constexpr int TM = BM / 32, TN = BN / 32;
  constexpr int NA = BM / 32;
  constexpr int NPASS = BM / 32;
  constexpr int NW = BN / 16;

  f32x4 acc[TM][TN];
#pragma unroll
  for (int m = 0; m < TM; ++m)
#pragma unroll
    for (int n = 0; n < TN; ++n) acc[m][n] = (f32x4){0.f, 0.f, 0.f, 0.f};

  const int nk = (K + BK - 1) / BK;
  for (int kt = 0; kt < nk; ++kt) {
    const int k0 = kt * BK;
    bf16x8 av[NA];
    f32x4 wv[NW];
    if (!GL) {
#pragma unroll
      for (int i = 0; i < NA; ++i) {
        int c = t + i * 256;
        int row = c >> 3, kc = c & 7;
        int kg = k0 + kc * 8;
        bf16x8 z = {};
        av[i] = (kg < K) ? *(const bf16x8*)(A + (size_t)(m0 + row) * K + kg) : z;
      }
    }
#pragma unroll
    for (int i = 0; i < NW; ++i) {
      int c = t + i * 256;
      int row = c >> 4, kc = c & 15;
      int kg = k0 + kc * 4;
      f32x4 z = (f32x4){0.f, 0.f, 0.f, 0.f};
      wv[i] = (kg < K) ? *(const f32x4*)(W + (size_t)(n0 + row) * K + kg) : z;
    }
    __syncthreads();
    if (GL) {
#pragma unroll
      for (int i = 0; i < NPASS; ++i) {
        int row = i * 32 + (t >> 3);
        int srcb = ((t & 7) * 16) ^ ((row & 7) << 4);
        const bf16* g2 = A + (size_t)(m0 + row) * K + k0 + (srcb >> 1);
        char* l = ldsA + i * 4096 + wid * 1024;
        __builtin_amdgcn_global_load_lds((const AS1 void*)g2, (AS3 void*)l, 16, 0, 0);
      }
    } else {
#pragma unroll
      for (int i = 0; i < NA; ++i) {
        int c = t + i * 256;
        int row = c >> 3, kc = c & 7;
        int kb = (kc * 16) ^ ((row & 7) << 4);
        *(bf16x8*)(ldsA + row * 128 + kb) = av[i];
      }
    }
#pragma unroll
    for (int i = 0; i < NW; ++i) {
      int c = t + i * 256;
      int row = c >> 4, kc = c & 15;
      bf16x4 bv;
      bv[0] = (bf16)wv[i][0]; bv[1] = (bf16)wv[i][1];
      bv[2] = (bf16)wv[i][2]; bv[3] = (bf16)wv[i][3];
      int kb = (kc * 8) ^ ((row & 7) << 4);
      *(bf16x4*)(ldsB + row * 128 + kb) = bv;
    }
    __syncthreads();
#pragma unroll
    for (int ks = 0; ks < 2; ++ks) {
      bf16x8 af[TM], bfr[TN];
      int kbb = ks * 64 + hi * 16;
#pragma unroll
      for (int m = 0; m < TM; ++m) {
        int row = wr * (BM / 2) + m * 16 + lo;
        af[m] = *(const bf16x8*)(ldsA + row * 128 + (kbb ^ ((row & 7) << 4)));
      }
#pragma unroll
      for (int n = 0; n < TN; ++n) {
        int row = wc * (BN / 2) + n * 16 + lo;
        bfr[n] = *(const bf16x8*)(ldsB + row * 128 + (kbb ^ ((row & 7) << 4)));
      }
#pragma unroll
      for (int m = 0; m < TM; ++m)
#pragma unroll
        for (int n = 0; n < TN; ++n)
          acc[m][n] = mfma16(af[m], bfr[n], acc[m][n]);
    }
    __syncthreads();
  }
#pragma unroll
  for (int m = 0; m < TM; ++m) {
    int gmb = m0 + wr * (BM / 2) + m * 16 + hi * 4;
#pragma unroll
    for (int n = 0; n < TN; ++n) {
      int gn = n0 + wc * (BN / 2) + n * 16 + lo;
#pragma unroll
      for (int r = 0; r < 4; ++r) {
        float v = acc[m][n][r];
        if (EPI == EPI_STORE) {
          C[(size_t)(gmb + r) * ldc + gn] = v;
        } else if (EPI == EPI_ADD) {
          C[(size_t)(gmb + r) * ldc + gn] += v;
        } else {
          float pv = __shfl_xor(v, 1);
          if (!(lane & 1)) {
            float g2 = fmaxf(v, 0.f);
            Cb[(size_t)(gmb + r) * (W13_N / 2) + (gn >> 1)] = (bf16)(g2 * g2 * pv);
          }
        }
      }
    }
  }
}

// ---------------- GEMM (mid): both A and W bf16, global_load_lds staged ----------------
// kLen = K-range per block (split-K via blockIdx.z); strideK = row stride.
// EPI_ADDA uses atomicAdd so split-K partials combine correctly (device scope).
template<int BM, int BN, int EPI>
__global__ __launch_bounds__(256) void gemm_bb(const bf16* __restrict__ A,
                                               const bf16* __restrict__ W,
                                               float* __restrict__ C, bf16* __restrict__ Cb,
                                               int strideK, int kLen, int ldc) {
  constexpr int BK = 64;
  __shared__ __align__(16) char lds[(BM + BN) * BK * 2];
  char* ldsA = lds;
  char* ldsB = lds + BM * BK * 2;
  const int t = threadIdx.x;
  int mtile, ntile;
  xcd_remap(gridDim.x, gridDim.y, mtile, ntile);
  const int m0 = mtile * BM, n0 = ntile * BN;
  const int koff = blockIdx.z * kLen;

  const int wid = t >> 6, lane = t & 63;
  const int lo = lane & 15, hi = lane >> 4;
  const int wr = wid >> 1, wc = wid & 1;
  constexpr int TM = BM / 32, TN = BN / 32;
  constexpr int PA = BM / 32, PB = BN / 32;

  f32x4 acc[TM][TN];
#pragma unroll
  for (int m = 0; m < TM; ++m)
#pragma unroll
    for (int n = 0; n < TN; ++n) acc[m][n] = (f32x4){0.f, 0.f, 0.f, 0.f};

  const int prow = t >> 3;
  const int psrcb = (t & 7) * 16;
  const int nk = kLen / BK;
  for (int kt = 0; kt < nk; ++kt) {
    const int k0 = koff + kt * BK;
#pragma unroll
    for (int i = 0; i < PA; ++i) {
      int row = i * 32 + prow;
      int srcb = psrcb ^ ((row & 7) << 4);
      const bf16* g = A + (size_t)(m0 + row) * strideK + k0 + (srcb >> 1);
      __builtin_amdgcn_global_load_lds((const AS1 void*)g,
                                       (AS3 void*)(ldsA + i * 4096 + wid * 1024), 16, 0, 0);
    }
#pragma unroll
    for (int i = 0; i < PB; ++i) {
      int row = i * 32 + prow;
      int srcb = psrcb ^ ((row & 7) << 4);
      const bf16* g = W + (size_t)(n0 + row) * strideK + k0 + (srcb >> 1);
      __builtin_amdgcn_global_load_lds((const AS1 void*)g,
                                       (AS3 void*)(ldsB + i * 4096 + wid * 1024), 16, 0, 0);
    }
    __syncthreads();
#pragma unroll
    for (int ks = 0; ks < 2; ++ks) {
      bf16x8 af[TM], bfr[TN];
      int kbb = ks * 64 + hi * 16;
#pragma unroll
      for (int m = 0; m < TM; ++m) {
        int row = wr * (BM / 2) + m * 16 + lo;
        af[m] = *(const bf16x8*)(ldsA + row * 128 + (kbb ^ ((row & 7) << 4)));
      }
#pragma unroll
      for (int n = 0; n < TN; ++n) {
        int row = wc * (BN / 2) + n * 16 + lo;
        bfr[n] = *(const bf16x8*)(ldsB + row * 128 + (kbb ^ ((row & 7) << 4)));
      }
#pragma unroll
      for (int m = 0; m < TM; ++m)
#pragma unroll
        for (int n = 0; n < TN; ++n)
          acc[m][n] = mfma16(af[m], bfr[n], acc[m][n]);
    }
    __syncthreads();
  }
#pragma unroll
  for (int m = 0; m < TM; ++m) {
    int gmb = m0 + wr * (BM / 2) + m * 16 + hi * 4;
#pragma unroll
    for (int n = 0; n < TN; ++n) {
      int gn = n0 + wc * (BN / 2) + n * 16 + lo;
#pragma unroll
      for (int r = 0; r < 4; ++r) {
        float v = acc[m][n][r];
        if (EPI == EPI_STORE) {
          C[(size_t)(gmb + r) * ldc + gn] = v;
        } else if (EPI == EPI_ADD) {
          C[(size_t)(gmb + r) * ldc + gn] += v;
        } else if (EPI == EPI_ADDA) {
          atomicAdd(&C[(size_t)(gmb + r) * ldc + gn], v);
        } else {
          float pv = __shfl_xor(v, 1);
          if (!(lane & 1)) {
            float g2 = fmaxf(v, 0.f);
            Cb[(size_t)(gmb + r) * (W13_N / 2) + (gn >> 1)] = (bf16)(g2 * g2 * pv);
          }
        }
      }
    }
  }
}

// ---------------- GEMM (big, fused fp32-W): 256x256, 8 waves, counted-vmcnt dbuf ----------
template<int EPI>
__global__ __launch_bounds__(512, 1) void gemm_2pf(const bf16* __restrict__ A,
                                                   const float* __restrict__ W,
                                                   float* __restrict__ C, bf16* __restrict__ Cb,
                                                   int K, int ldc) {
  extern __shared__ __align__(16) char lds[];
  char* ldsA = lds;            // [2 buf][2 half][128 rows][128 B] = 64 KB
  char* ldsB = lds + 65536;
  const int t = threadIdx.x;
  int mtile, ntile;
  xcd_remap(gridDim.x, gridDim.y, mtile, ntile);
  const int m0 = mtile * 256, n0 = ntile * 256;
  const int wid = t >> 6, lane = t & 63;
  const int lo = lane & 15, hi = lane >> 4;
  const int wr = wid >> 2, wc = wid & 3;

  f32x4 acc[8][4];
#pragma unroll
  for (int f = 0; f < 8; ++f)
#pragma unroll
    for (int g = 0; g < 4; ++g) acc[f][g] = (f32x4){0.f, 0.f, 0.f, 0.f};

  const int prow = t >> 3;
  const int pcol = (t & 7) * 16;

  auto STAGEA = [&](int h, int kt2) {
    char* dst = ldsA + (kt2 & 1) * 32768 + h * 16384;
    const int k0 = kt2 * 64;
#pragma unroll
    for (int i = 0; i < 2; ++i) {
      int row = i * 64 + prow;
      int srcb = pcol ^ ((row & 7) << 4);
      const bf16* g = A + (size_t)(m0 + h * 128 + row) * K + k0 + (srcb >> 1);
      __builtin_amdgcn_global_load_lds((const AS1 void*)g,
          (AS3 void*)(dst + i * 8192 + wid * 1024), 16, 0, 0);
    }
  };

  f32x4 breg[4][2];
  auto BLOAD = [&](int kt2) {
#pragma unroll
    for (int i = 0; i < 4; ++i) {
      int c = t + i * 512;
      int row = c >> 3, kc = c & 7;
      const float* g = W + (size_t)(n0 + row) * K + kt2 * 64 + kc * 8;
      breg[i][0] = *(const f32x4*)(g);
      breg[i][1] = *(const f32x4*)(g + 4);
    }
  };
  auto BWRITE = [&](int kt2) {
#pragma unroll
    for (int i = 0; i < 4; ++i) {
      int c = t + i * 512;
      int row = c >> 3, kc = c & 7;
      int h = row >> 7, rowh = row & 127;
      bf16x8 bv;
#pragma unroll
      for (int e = 0; e < 4; ++e) {
        bv[e]     = (bf16)breg[i][0][e];
        bv[4 + e] = (bf16)breg[i][1][e];
      }
      *(bf16x8*)(ldsB + (kt2 & 1) * 32768 + h * 16384 + rowh * 128 +
                 ((kc * 16) ^ ((rowh & 7) << 4))) = bv;
    }
  };

  auto LDA = [&](int buf, int mh, int i, int ks) -> bf16x8 {
    int row = (mh * 4 + i) * 16 + lo;
    return *(const bf16x8*)(ldsA + buf * 32768 + wr * 16384 + row * 128 +
                            ((ks * 64 + hi * 16) ^ ((row & 7) << 4)));
  };
  auto LDB = [&](int buf, int nh, int j, int ks) -> bf16x8 {
    int rowh = (wc & 1) * 64 + (nh * 2 + j) * 16 + lo;
    return *(const bf16x8*)(ldsB + buf * 32768 + (wc >> 1) * 16384 + rowh * 128 +
                            ((ks * 64 + hi * 16) ^ ((rowh & 7) << 4)));
  };

  const int nk = K / 64;
  STAGEA(0, 0);
  STAGEA(1, 0);
  __builtin_amdgcn_sched_barrier(0);
  BLOAD(0);
  __builtin_amdgcn_sched_barrier(0);
  asm volatile("s_waitcnt vmcnt(8)" ::: "memory");
  __builtin_amdgcn_s_barrier();
  asm volatile("" ::: "memory");

  for (int kt = 0; kt < nk; ++kt) {
    const int buf = kt & 1;
    const bool more = (kt + 1) < nk;
    BWRITE(kt);
    asm volatile("s_waitcnt lgkmcnt(0)" ::: "memory");
    __builtin_amdgcn_s_barrier();
    asm volatile("" ::: "memory");
    if (more) {
      STAGEA(0, kt + 1);
      STAGEA(1, kt + 1);
      __builtin_amdgcn_sched_barrier(0);
      BLOAD(kt + 1);
      __builtin_amdgcn_sched_barrier(0);
    }
#pragma unroll
    for (int mh = 0; mh < 2; ++mh) {
      bf16x8 a[4][2];
#pragma unroll
      for (int i = 0; i < 4; ++i) { a[i][0] = LDA(buf, mh, i, 0); a[i][1] = LDA(buf, mh, i, 1); }
#pragma unroll
      for (int nh = 0; nh < 2; ++nh) {
        bf16x8 b[2][2];
#pragma unroll
        for (int j = 0; j < 2; ++j) { b[j][0] = LDB(buf, nh, j, 0); b[j][1] = LDB(buf, nh, j, 1); }
        __builtin_amdgcn_s_setprio(1);
#pragma unroll
        for (int i = 0; i < 4; ++i)
#pragma unroll
          for (int j = 0; j < 2; ++j) {
            acc[mh * 4 + i][nh * 2 + j] = mfma16(a[i][0], b[j][0], acc[mh * 4 + i][nh * 2 + j]);
            acc[mh * 4 + i][nh * 2 + j] = mfma16(a[i][1], b[j][1], acc[mh * 4 + i][nh * 2 + j]);
          }
        __builtin_amdgcn_s_setprio(0);
      }
    }
    if (more) asm volatile("s_waitcnt vmcnt(8)" ::: "memory");
    else      asm volatile("s_waitcnt vmcnt(0)" ::: "memory");
    __builtin_amdgcn_s_barrier();
    asm volatile("" ::: "memory");
  }
#pragma unroll
  for (int f = 0; f < 8; ++f) {
    int gmb = m0 + wr * 128 + f * 16 + hi * 4;
#pragma unroll
    for (int g = 0; g < 4; ++g) {
      int gn = n0 + wc * 64 + g * 16 + lo;
#pragma unroll
      for (int r = 0; r < 4; ++r) {
        float v = acc[f][g][r];
        if (EPI == EPI_STORE) {
          C[(size_t)(gmb + r) * ldc + gn] = v;
        } else if (EPI == EPI_ADD) {
          C[(size_t)(gmb + r) * ldc + gn] += v;
        } else {
          float pv = __shfl_xor(v, 1);
          if (!(lane & 1)) {
            float g2 = fmaxf(v, 0.f);
            Cb[(size_t)(gmb + r) * (W13_N / 2) + (gn >> 1)] = (bf16)(g2 * g2 * pv);
          }
        }
      }
    }
  }
}

// ---------------- launch ----------------
extern "C" void kernel_launch(void* const* d_in, const int* in_sizes, int n_in,
                              void* d_out, int out_size, void* d_ws, size_t ws_size,
                              hipStream_t stream) {
  const int* tokens = (const int*)d_in[0];
  const float* img_feats = (const float*)d_in[1];
  const float* freqs = (const float*)d_in[2];
  const float* freqs2 = (const float*)d_in[3];
  const float* tok_emb = (const float*)d_in[4];
  const float* img_proj_w = (const float*)d_in[5];
  const float* wqkv = (const float*)d_in[6];
  const float* wo = (const float*)d_in[7];
  const float* sinks = (const float*)d_in[8];
  const float* w13 = (const float*)d_in[9];
  const float* w2 = (const float*)d_in[10];
  const float* norm_w = (const float*)d_in[11];
  const float* output_w = (const float*)d_in[12];
  float* out = (float*)d_out;

  char* ws = (char*)d_ws;
  float* x = (float*)ws;   ws += (size_t)S_LEN * DIM * 4;
  bf16* h = (bf16*)ws;     ws += (size_t)S_LEN * DIM * 2;
  float* qkv = (float*)ws; ws += (size_t)S_LEN * QKV_N * 4;
  bf16* qb = (bf16*)ws;    ws += (size_t)NH * S_LEN * HD * 2;
  bf16* kb = (bf16*)ws;    ws += (size_t)NKVH * S_LEN * HD * 2;
  bf16* vtb = (bf16*)ws;   ws += (size_t)NKVH * HD * S_LEN * 2;
  bf16* ao = (bf16*)ws;    ws += (size_t)S_LEN * DIM * 2;
  bf16* act = (bf16*)ws;   ws += (size_t)S_LEN * HID * 2;
  bf16* imgb = (bf16*)ws;  ws += (size_t)NIMG * IMG_K * 2;
  const size_t n_wqkv = (size_t)2 * QKV_N * DIM;
  const size_t n_wo   = (size_t)2 * DIM * (NH * HD);
  const size_t n_w2   = (size_t)2 * DIM * HID;
  bf16* wqkvb = (bf16*)ws; ws += n_wqkv * 2;
  bf16* wob   = (bf16*)ws; ws += n_wo * 2;
  bf16* w2b   = (bf16*)ws; ws += n_w2 * 2;
  const bool bf16_path = ((size_t)(ws - (char*)d_ws) <= ws_size);

  bool big_ok = false;
  {
    hipError_t e1 = hipFuncSetAttribute((const void*)&gemm_2pf<EPI_STORE>,
                                        hipFuncAttributeMaxDynamicSharedMemorySize, 131072);
    hipError_t e2 = hipFuncSetAttribute((const void*)&gemm_2pf<EPI_ACT>,
                                        hipFuncAttributeMaxDynamicSharedMemorySize, 131072);
    if (e1 == hipSuccess && e2 == hipSuccess) {
      hipFuncAttributes fa1{}, fa2{};
      if (hipFuncGetAttributes(&fa1, (const void*)&gemm_2pf<EPI_STORE>) == hipSuccess &&
          hipFuncGetAttributes(&fa2, (const void*)&gemm_2pf<EPI_ACT>) == hipSuccess)
        big_ok = fa1.maxDynamicSharedSizeBytes >= 131072 &&
                 fa2.maxDynamicSharedSizeBytes >= 131072;
    }
  }

  embed_kernel<<<S_LEN, 256, 0, stream>>>(tokens, tok_emb, x);
  cvt_kernel<<<(NIMG * IMG_K + 255) / 256, 256, 0, stream>>>(img_feats, imgb, NIMG * IMG_K);
  gemm_bt<64, 128, EPI_STORE, 0><<<dim3(NIMG / 64, DIM / 128), 256, 0, stream>>>(
      imgb, img_proj_w, x + DIM, nullptr, NIMG, DIM, IMG_K, DIM);

  if (bf16_path) {
    cvt4_kernel<<<(int)(n_wqkv / 4 + 255) / 256, 256, 0, stream>>>(wqkv, wqkvb, (int)(n_wqkv / 4));
    cvt4_kernel<<<(int)(n_wo / 4 + 255) / 256, 256, 0, stream>>>(wo, wob, (int)(n_wo / 4));
    cvt4_kernel<<<(int)(n_w2 / 4 + 255) / 256, 256, 0, stream>>>(w2, w2b, (int)(n_w2 / 4));
  }

  for (int i = 0; i < 2; ++i) {
    rmsnorm_kernel<0><<<S_LEN, 256, 0, stream>>>(x, nullptr, h);
    if (bf16_path) {
      gemm_bb<64, 128, EPI_STORE><<<dim3(S_LEN / 64, QKV_N / 128, 1), 256, 0, stream>>>(
          h, wqkvb + (size_t)i * QKV_N * DIM, qkv, nullptr, DIM, DIM, QKV_N);
    } else {
      gemm_bt<64, 128, EPI_STORE, 1><<<dim3(S_LEN / 64, QKV_N / 128), 256, 0, stream>>>(
          h, wqkv + (size_t)i * QKV_N * DIM, qkv, nullptr, S_LEN, QKV_N, DIM, QKV_N);
    }
    qkvpost_kernel<<<S_LEN, 256, 0, stream>>>(qkv, freqs, freqs2, qb, kb, vtb);
    attn_kernel<<<dim3(S_LEN / 16, NH), 256, 0, stream>>>(qb, kb, vtb, sinks + i * NH, ao);
    if (bf16_path) {
      // split-K=2: 512 blocks (2/CU) for implicit stage/compute overlap
      gemm_bb<64, 128, EPI_ADDA><<<dim3(S_LEN / 64, DIM / 128, 2), 256, 0, stream>>>(
          ao, wob + (size_t)i * DIM * DIM, x, nullptr, DIM, DIM / 2, DIM);
    } else {
      gemm_bt<64, 128, EPI_ADD, 1><<<dim3(S_LEN / 64, DIM / 128), 256, 0, stream>>>(
          ao, wo + (size_t)i * DIM * DIM, x, nullptr, S_LEN, DIM, DIM, DIM);
    }
    rmsnorm_kernel<0><<<S_LEN, 256, 0, stream>>>(x, nullptr, h);
    if (big_ok) {
      gemm_2pf<EPI_ACT><<<dim3(S_LEN / 256, W13_N / 256), 512, 131072, stream>>>(
          h, w13 + (size_t)i * W13_N * DIM, nullptr, act, DIM, 0);
    } else {
      gemm_bt<128, 128, EPI_ACT, 1><<<dim3(S_LEN / 128, W13_N / 128), 256, 0, stream>>>(
          h, w13 + (size_t)i * W13_N * DIM, nullptr, act, S_LEN, W13_N, DIM, 0);
    }
    if (bf16_path) {
      gemm_bb<64, 128, EPI_ADDA><<<dim3(S_LEN / 64, DIM / 128, 2), 256, 0, stream>>>(
          act, w2b + (size_t)i * DIM * HID, x, nullptr, HID, HID / 2, DIM);
    } else {
      gemm_bt<64, 128, EPI_ADD, 1><<<dim3(S_LEN / 64, DIM / 128), 256, 0, stream>>>(
          act, w2 + (size_t)i * DIM * HID, x, nullptr, S_LEN, DIM, HID, DIM);
    }
  }
  rmsnorm_kernel<1><<<S_LEN, 256, 0, stream>>>(x, norm_w, h);
  if (big_ok) {
    gemm_2pf<EPI_STORE><<<dim3(S_LEN / 256, VOCAB / 256), 512, 131072, stream>>>(
        h, output_w, out, nullptr, DIM, VOCAB);
  } else {
    gemm_bt<128, 128, EPI_STORE, 1><<<dim3(S_LEN / 128, VOCAB / 128), 256, 0, stream>>>(
        h, output_w, out, nullptr, S_LEN, VOCAB, DIM, VOCAB);
  }
}